// Round 14
// baseline (215.039 us; speedup 1.0000x reference)
//
#include <hip/hip_runtime.h>

// ---------------------------------------------------------------------------
// qkv = x@W_attn; RoPE(q,k); flash-attn; y@W_proj
// B=2, T=2048, C=1024, H=16, HD=64.  I/O fp32; internal tensors bf16.
//
// R25 (R24 measured 212.36us; attn merged dispatch 56.3us, VALUBusy 50.6%,
// Occ 21.7%, LDS 49KB -> LDS/launch_bounds is the only thing holding attn at
// 2 blocks/CU; 3 fit in 147KB):
//  * occupancy hints only, zero math change:
//      attn_k:  __launch_bounds__(256,2) -> (256,3)   [3 x 49KB = 147 <= 160]
//      gemm1:   (256,3) -> (256,4)                    [4 x 24KB = 96]
//      gemm2:   (256,2) -> (256,4)                    [4 x 16KB = 64]
//    VGPR caps (170/128/128) far above measured use (68/56/~40) -> no spill.
//  * everything else byte-identical to measured R24.
// ---------------------------------------------------------------------------

typedef __attribute__((ext_vector_type(8))) short short8;   // 8 bf16 = 4 VGPRs
typedef __attribute__((ext_vector_type(4))) float floatx4;  // MFMA C/D frag

__device__ __forceinline__ ushort f2bf(float f) {
    unsigned x = __float_as_uint(f);
    x += 0x7fffu + ((x >> 16) & 1u);   // round-to-nearest-even
    return (ushort)(x >> 16);
}
__device__ __forceinline__ float bf2f(ushort u) {
    return __uint_as_float(((unsigned)u) << 16);
}

#define MFMA16(a, b, c) __builtin_amdgcn_mfma_f32_16x16x32_bf16((a), (b), (c), 0, 0, 0)

// async global->LDS, 16 bytes per lane.  LDS dest must be wave-uniform base;
// HW writes base + lane*16.  Global src is per-lane.
__device__ __forceinline__ void glds16(const ushort* g, ushort* l) {
    __builtin_amdgcn_global_load_lds(
        (const __attribute__((address_space(1))) unsigned int*)g,
        (__attribute__((address_space(3))) unsigned int*)l, 16, 0, 0);
}

// ---------------------------------------------------------------------------
// Transpose + cvt: src f32 [R][C] -> dst bf16 [C][R].  32x32 tiles via LDS.
// ---------------------------------------------------------------------------
__global__ __launch_bounds__(256) void tp_k(const float* __restrict__ src,
                                            ushort* __restrict__ dst,
                                            int R, int C) {
    __shared__ ushort t[32][34];
    const int c0 = blockIdx.x * 32, r0 = blockIdx.y * 32;
    const int tr = threadIdx.x >> 5, tc = threadIdx.x & 31;
#pragma unroll
    for (int j = 0; j < 4; j++)
        t[tr + j * 8][tc] = f2bf(src[(size_t)(r0 + tr + j * 8) * C + c0 + tc]);
    __syncthreads();
#pragma unroll
    for (int j = 0; j < 4; j++)
        dst[(size_t)(c0 + tr + j * 8) * R + r0 + tc] = t[tc][tr + j * 8];
}

// ---------------------------------------------------------------------------
// cvt: f32 -> bf16, 4 elems/thread.
// ---------------------------------------------------------------------------
__global__ __launch_bounds__(256) void cvt_k(const float* __restrict__ src,
                                             ushort* __restrict__ dst) {
    const size_t i = ((size_t)blockIdx.x * 256 + threadIdx.x) * 4;
    float4 t4 = *(const float4*)&src[i];
    *(ushort4*)&dst[i] = make_ushort4(f2bf(t4.x), f2bf(t4.y), f2bf(t4.z), f2bf(t4.w));
}

// ---------------------------------------------------------------------------
// trig table: tab[t][j] = (cos(t * 10000^(-j/32)), sin(...)), f64 math
// identical to the original in-rope computation (bit-identical results).
// ---------------------------------------------------------------------------
__global__ __launch_bounds__(256) void trig_k(float2* __restrict__ tab) {
    const int idx = blockIdx.x * 256 + threadIdx.x;   // [0, 65536)
    const int t = idx >> 5, j = idx & 31;
    const double inv = pow(10000.0, -(double)j / 32.0);
    const double ang = (double)t * inv;
    tab[idx] = make_float2((float)cos(ang), (float)sin(ang));
}

// ---------------------------------------------------------------------------
// GEMM1: qkv = xb[2048][1024](bf16) @ WaT^T (Bt bf16 [3072][1024])
//   -> q: [H,T,HD]  k: [H,T,HD]  v^T: [H,HD,T]  (bf16)
// R15/R18 form (measured best): 128x64 tile, BK=64, glds16, swizzled LDS.
// R24: batch from blockIdx.z.  R25: 4 blocks/CU.
// ---------------------------------------------------------------------------
__global__ __launch_bounds__(256, 4) void gemm1_qkv_k(const ushort* __restrict__ Ab,
                                                      const ushort* __restrict__ Bt,
                                                      ushort* __restrict__ qb,
                                                      ushort* __restrict__ kb,
                                                      ushort* __restrict__ vtb) {
    __shared__ __align__(16) ushort As[128 * 64];  // 16 KB, linear+swizzled
    __shared__ __align__(16) ushort Bs[64 * 64];   // 8 KB
    const size_t boff = (size_t)blockIdx.z * (2048u * 1024u);
    Ab += boff; qb += boff; kb += boff; vtb += boff;
    const int tid = threadIdx.x;
    const int m0 = blockIdx.y * 128, n0 = blockIdx.x * 64;
    const int w = tid >> 6, lane = tid & 63, quad = lane >> 4, l16 = lane & 15;
    const int wr = w >> 1, wc = w & 1;
    const int K = 1024;
    const int srow = lane >> 3, sslot = lane & 7;  // staging sub-row / slot

    floatx4 acc[4][2];
#pragma unroll
    for (int mt = 0; mt < 4; mt++)
#pragma unroll
        for (int nt = 0; nt < 2; nt++) acc[mt][nt] = (floatx4){0.f, 0.f, 0.f, 0.f};

    for (int k0 = 0; k0 < K; k0 += 64) {
        __syncthreads();   // all waves done reading prev tile
#pragma unroll
        for (int jj = 0; jj < 4; jj++) {
            const int reg = jj * 4 + w;
            const int row = reg * 8 + srow;
            const int cs = sslot ^ (row & 7);
            glds16(&Ab[(size_t)(m0 + row) * K + k0 + cs * 8], &As[reg * 512]);
        }
#pragma unroll
        for (int jj = 0; jj < 2; jj++) {
            const int reg = jj * 4 + w;
            const int row = reg * 8 + srow;
            const int cs = sslot ^ (row & 7);
            glds16(&Bt[(size_t)(n0 + row) * K + k0 + cs * 8], &Bs[reg * 512]);
        }
        __syncthreads();   // compiler drains vmcnt(0) before barrier

#pragma unroll
        for (int kk = 0; kk < 2; kk++) {
            short8 af[4], bfr[2];
#pragma unroll
            for (int mt = 0; mt < 4; mt++) {
                const int row = wr * 64 + mt * 16 + l16;
                const int slot = ((kk << 2) | quad) ^ (row & 7);
                af[mt] = *(short8*)&As[row * 64 + slot * 8];
            }
#pragma unroll
            for (int nt = 0; nt < 2; nt++) {
                const int row = wc * 32 + nt * 16 + l16;
                const int slot = ((kk << 2) | quad) ^ (row & 7);
                bfr[nt] = *(short8*)&Bs[row * 64 + slot * 8];
            }
#pragma unroll
            for (int mt = 0; mt < 4; mt++)
#pragma unroll
                for (int nt = 0; nt < 2; nt++) acc[mt][nt] = MFMA16(af[mt], bfr[nt], acc[mt][nt]);
        }
    }

    // Epilogue [R5-R10 verified formulas; nt bound 2, wave n-stride 32]
#pragma unroll
    for (int nt = 0; nt < 2; nt++) {
        const int n = n0 + wc * 32 + nt * 16 + l16;
        const int seg = n >> 10;          // 0=q 1=k 2=v
        const int cn = n & 1023;
        const int h = cn >> 6, d = cn & 63;
#pragma unroll
        for (int mt = 0; mt < 4; mt++) {
#pragma unroll
            for (int r = 0; r < 4; r++) {
                const int t = m0 + wr * 64 + mt * 16 + quad * 4 + r;
                const ushort v = f2bf(acc[mt][nt][r]);
                if (seg == 0)      qb[((size_t)h * 2048 + t) * 64 + d] = v;
                else if (seg == 1) kb[((size_t)h * 2048 + t) * 64 + d] = v;
                else               vtb[((size_t)h * 64 + d) * 2048 + t] = v;
            }
        }
    }
}

// ---------------------------------------------------------------------------
// RoPE (roll variant), table-based trig.  Math identical to verified R5-R11.
// Row index spans batches naturally (row = (b*16+h)*2048 + t; t = wid&2047).
// ---------------------------------------------------------------------------
__global__ __launch_bounds__(256) void rope_k(ushort* __restrict__ q,
                                              ushort* __restrict__ k,
                                              const float2* __restrict__ tab) {
    const int wid = blockIdx.x * 4 + (threadIdx.x >> 6);  // row
    const int lane = threadIdx.x & 63;
    const int t = wid & 2047;
    const float2 cs = tab[t * 32 + (lane & 31)];
    const float c = cs.x;
    const float s = cs.y;
    const size_t base = (size_t)wid * 64;

    float qv = bf2f(q[base + lane]);
    float qp = __shfl(qv, (lane + 63) & 63, 64);
    q[base + lane] = f2bf(qv * c + qp * s);

    float kv = bf2f(k[base + lane]);
    float kp = __shfl(kv, (lane + 63) & 63, 64);
    k[base + lane] = f2bf(kv * c + kp * s);
}

// ---------------------------------------------------------------------------
// Flash attention (causal), transposed form.
// R12: one q-tile per block.  R13: no Ps barrier.  R14: balanced qt remap.
// R21: KVBLK=128 + glds16 staging + exact-skip defer-max + setprio.
// R24: batch = bid>>9 (grid 1024 merged / 512 fallback).
// R25: 3 blocks/CU (147KB LDS <= 160).
// ---------------------------------------------------------------------------
__global__ __launch_bounds__(256, 3) void attn_k(const ushort* __restrict__ q,
                                                 const ushort* __restrict__ k,
                                                 const ushort* __restrict__ vt,
                                                 ushort* __restrict__ y) {
    __shared__ __align__(16) ushort Ks[128 * 64];   // [key][d]  16 KB swz
    __shared__ __align__(16) ushort Vs[64 * 128];   // [d][key]  16 KB swz
    __shared__ __align__(16) ushort Ps[4][16][136]; // per-wave P^T [qrow][key]

    const int bid = blockIdx.x;
    const int b = bid >> 9;            // batch (0 under fallback grid 512)
    const int r9 = bid & 511;
    // r9 0..255: qt = 31,30,..,16 (16 heads each); 256..511: qt = 0,1,..,15
    const int qt = (r9 < 256) ? (31 - (r9 >> 4)) : ((r9 >> 4) - 16);
    const int h = r9 & 15;
    const size_t boff = (size_t)b * (2048u * 1024u);
    q += boff; k += boff; vt += boff; y += boff;
    const int tid = threadIdx.x, w = tid >> 6, lane = tid & 63;
    const int quad = lane >> 4, l16 = lane & 15;
    const int srow8 = lane >> 3, sslot8 = lane & 7;   // K staging (8 rows/KB)
    const int srow4 = lane >> 4, sslot16 = lane & 15; // V staging (4 rows/KB)

    const int q0 = qt * 64;
    const int qrow = q0 + w * 16 + l16;
    const int nkt = (qt >> 1) + 1;     // 128-key tiles; trailing keys masked

    short8 qa0, qa1;
    {
        const ushort* qp = q + ((size_t)h * 2048 + qrow) * 64 + quad * 8;
        qa0 = *(const short8*)(qp);
        qa1 = *(const short8*)(qp + 32);
    }

    floatx4 O[4];
#pragma unroll
    for (int dt = 0; dt < 4; dt++) O[dt] = (floatx4){0.f, 0.f, 0.f, 0.f};
    float M = -30000.f, L = 0.f;

    for (int kt2 = 0; kt2 < nkt; kt2++) {
        const int kbase = kt2 * 128;
        __syncthreads();   // all waves done reading prev tile's LDS
        // K: 128 rows x 64 (128B rows, 8 chunks), 16 regions of 8 rows.
#pragma unroll
        for (int jj = 0; jj < 4; jj++) {
            const int reg = jj * 4 + w;
            const int row = reg * 8 + srow8;
            const int cs = sslot8 ^ (row & 7);
            glds16(&k[((size_t)h * 2048 + kbase + row) * 64 + cs * 8], &Ks[reg * 512]);
        }
        // V^T: 64 rows x 128 (256B rows, 16 chunks), 16 regions of 4 rows.
#pragma unroll
        for (int jj = 0; jj < 4; jj++) {
            const int reg = jj * 4 + w;
            const int row = reg * 4 + srow4;
            const int cs = sslot16 ^ (row & 15);
            glds16(&vt[((size_t)h * 64 + row) * 2048 + kbase + cs * 8], &Vs[reg * 512]);
        }
        __syncthreads();   // staging complete (vmcnt(0) drained at barrier)

        floatx4 s[8];
        __builtin_amdgcn_s_setprio(1);   // T5: QK^T MFMA cluster
#pragma unroll
        for (int nt = 0; nt < 8; nt++) {
            const int row = nt * 16 + l16;
            short8 ka0 = *(short8*)&Ks[row * 64 + ((quad ^ (row & 7)) * 8)];
            short8 ka1 = *(short8*)&Ks[row * 64 + (((4 | quad) ^ (row & 7)) * 8)];
            floatx4 z = (floatx4){0.f, 0.f, 0.f, 0.f};
            z = MFMA16(ka0, qa0, z);
            z = MFMA16(ka1, qa1, z);
            s[nt] = z;
        }
        __builtin_amdgcn_s_setprio(0);

        // scale + unconditional causal mask  [R17-verified]
#pragma unroll
        for (int nt = 0; nt < 8; nt++)
#pragma unroll
            for (int r = 0; r < 4; r++) {
                const int kidx = kbase + nt * 16 + quad * 4 + r;
                const float vv = s[nt][r] * 0.125f;
                s[nt][r] = (kidx > qrow) ? -30000.f : vv;
            }

        // tree max over 32 values (max is exactly associative)
        float mr[8];
#pragma unroll
        for (int nt = 0; nt < 8; nt++)
            mr[nt] = fmaxf(fmaxf(s[nt][0], s[nt][1]), fmaxf(s[nt][2], s[nt][3]));
        float mx = fmaxf(fmaxf(fmaxf(mr[0], mr[1]), fmaxf(mr[2], mr[3])),
                         fmaxf(fmaxf(mr[4], mr[5]), fmaxf(mr[6], mr[7])));
        mx = fmaxf(mx, __shfl_xor(mx, 16, 64));
        mx = fmaxf(mx, __shfl_xor(mx, 32, 64));

        // exact-skip defer-max: if no lane's max grew, Mn==M and alpha==1
        // exactly -> skipping rescale is bit-identical.
        if (!__all(mx <= M)) {
            const float Mn = fmaxf(M, mx);
            const float alpha = __expf(M - Mn);
            L *= alpha;
#pragma unroll
            for (int dt = 0; dt < 4; dt++) O[dt] *= alpha;
            M = Mn;
        }

        float sum = 0.f;
#pragma unroll
        for (int nt = 0; nt < 8; nt++)
#pragma unroll
            for (int r = 0; r < 4; r++) {
                const float pv = __expf(s[nt][r] - M);
                s[nt][r] = pv;
                sum += pv;
            }
        sum += __shfl_xor(sum, 16, 64);
        sum += __shfl_xor(sum, 32, 64);
        L += sum;

#pragma unroll
        for (int nt = 0; nt < 8; nt++) {
            ushort4 pk = make_ushort4(f2bf(s[nt][0]), f2bf(s[nt][1]),
                                      f2bf(s[nt][2]), f2bf(s[nt][3]));
            *(ushort4*)&Ps[w][l16][nt * 16 + quad * 4] = pk;
        }
        // no barrier: Ps[w] is written and read only by wave w; in-wave DS
        // ordering is enforced by the compiler's lgkmcnt tracking.

        short8 pb[4];
#pragma unroll
        for (int ks = 0; ks < 4; ks++)
            pb[ks] = *(short8*)&Ps[w][l16][ks * 32 + quad * 8];
        __builtin_amdgcn_s_setprio(1);   // T5: PV MFMA cluster
#pragma unroll
        for (int dt = 0; dt < 4; dt++) {
            const int row = dt * 16 + l16;
#pragma unroll
            for (int ks = 0; ks < 4; ks++) {
                const int cc = (ks * 4 + quad) ^ (row & 15);
                short8 va = *(short8*)&Vs[row * 128 + cc * 8];
                O[dt] = MFMA16(va, pb[ks], O[dt]);
            }
        }
        __builtin_amdgcn_s_setprio(0);
    }

    const float rl = 1.0f / L;
#pragma unroll
    for (int dt = 0; dt < 4; dt++) {
        ushort4 o4 = make_ushort4(f2bf(O[dt][0] * rl), f2bf(O[dt][1] * rl),
                                  f2bf(O[dt][2] * rl), f2bf(O[dt][3] * rl));
        *(ushort4*)&y[(size_t)qrow * 1024 + h * 64 + dt * 16 + quad * 4] = o4;
    }
}

// ---------------------------------------------------------------------------
// GEMM2: out(f32) = y[2048][1024](bf16) @ WpT^T (bf16 [1024][1024])
// R15/R18 form (measured best): 64x64 tile, BK=64, glds16, swizzled LDS.
// R24: batch from blockIdx.z.  R25: 4 blocks/CU.
// ---------------------------------------------------------------------------
__global__ __launch_bounds__(256, 4) void gemm2_proj_k(const ushort* __restrict__ Y,
                                                       const ushort* __restrict__ Bt,
                                                       float* __restrict__ out) {
    __shared__ __align__(16) ushort As[64 * 64];   // 8 KB, linear+swizzled
    __shared__ __align__(16) ushort Bs[64 * 64];   // 8 KB
    const size_t boff = (size_t)blockIdx.z * (2048u * 1024u);
    Y += boff; out += boff;
    const int tid = threadIdx.x;
    const int m0 = blockIdx.y * 64, n0 = blockIdx.x * 64;
    const int w = tid >> 6, lane = tid & 63, quad = lane >> 4, l16 = lane & 15;
    const int wr = w >> 1, wc = w & 1;
    const int K = 1024;
    const int srow = lane >> 3, sslot = lane & 7;

    floatx4 acc[2][2];
#pragma unroll
    for (int mt = 0; mt < 2; mt++)
#pragma unroll
        for (int nt = 0; nt < 2; nt++) acc[mt][nt] = (floatx4){0.f, 0.f, 0.f, 0.f};

    for (int k0 = 0; k0 < K; k0 += 64) {
        __syncthreads();
#pragma unroll
        for (int jj = 0; jj < 2; jj++) {
            const int reg = jj * 4 + w;
            const int row = reg * 8 + srow;
            const int cs = sslot ^ (row & 7);
            glds16(&Y[(size_t)(m0 + row) * K + k0 + cs * 8], &As[reg * 512]);
            glds16(&Bt[(size_t)(n0 + row) * K + k0 + cs * 8], &Bs[reg * 512]);
        }
        __syncthreads();

#pragma unroll
        for (int kk = 0; kk < 2; kk++) {
            short8 af[2], bfr[2];
#pragma unroll
            for (int mt = 0; mt < 2; mt++) {
                const int row = wr * 32 + mt * 16 + l16;
                const int slot = ((kk << 2) | quad) ^ (row & 7);
                af[mt] = *(short8*)&As[row * 64 + slot * 8];
            }
#pragma unroll
            for (int nt = 0; nt < 2; nt++) {
                const int row = wc * 32 + nt * 16 + l16;
                const int slot = ((kk << 2) | quad) ^ (row & 7);
                bfr[nt] = *(short8*)&Bs[row * 64 + slot * 8];
            }
#pragma unroll
            for (int mt = 0; mt < 2; mt++)
#pragma unroll
                for (int nt = 0; nt < 2; nt++) acc[mt][nt] = MFMA16(af[mt], bfr[nt], acc[mt][nt]);
        }
    }

#pragma unroll
    for (int mt = 0; mt < 2; mt++)
#pragma unroll
        for (int nt = 0; nt < 2; nt++) {
            const int n = n0 + wc * 32 + nt * 16 + l16;
#pragma unroll
            for (int r = 0; r < 4; r++) {
                const int m = m0 + wr * 32 + mt * 16 + quad * 4 + r;
                out[(size_t)m * 1024 + n] = acc[mt][nt][r];
            }
        }
}

// ---------------------------------------------------------------------------
extern "C" void kernel_launch(void* const* d_in, const int* in_sizes, int n_in,
                              void* d_out, int out_size, void* d_ws, size_t ws_size,
                              hipStream_t stream) {
    const float* x  = (const float*)d_in[0];   // [2,2048,1024] f32
    const float* Wa = (const float*)d_in[1];   // [1024,3072]  f32
    const float* Wp = (const float*)d_in[2];   // [1024,1024]  f32
    float* out = (float*)d_out;                // [2,2048,1024] f32

    const size_t PB = (size_t)2048 * 1024;     // per-batch elements
    ushort* wtA = (ushort*)(out + PB);         // 6 MB W_attn^T bf16 (d_out b1
                                               //  half; dead after gemm1, and
                                               //  gemm2-b1 fully overwrites it)
    float2* tab = (float2*)(wtA + (size_t)3 * 1024 * 1024);
                                               // 512 KB trig table (d_out b1
                                               //  tail; dead after rope)

    if (ws_size >= (size_t)36 * 1024 * 1024) {
        // -------- merged-batch path: 8 launches ---------------------------
        ushort* qbA = (ushort*)d_ws;           // [2] x 4 MB  q  [b][H,T,HD]
        ushort* kbA = qbA + 2 * PB;            // [2] x 4 MB  k
        ushort* vtA = qbA + 4 * PB;            // [2] x 4 MB  v^T
        ushort* ybA = qbA + 6 * PB;            // [2] x 4 MB  x_bf16 / y
        ushort* wtP = qbA + 8 * PB;            // 2 MB  W_proj^T

        tp_k<<<dim3(96, 32), 256, 0, stream>>>(Wa, wtA, 1024, 3072);
        trig_k<<<dim3(256), 256, 0, stream>>>(tab);
        tp_k<<<dim3(32, 32), 256, 0, stream>>>(Wp, wtP, 1024, 1024);

        cvt_k<<<dim3(4096), 256, 0, stream>>>(x, ybA);
        gemm1_qkv_k<<<dim3(48, 16, 2), 256, 0, stream>>>(ybA, wtA, qbA, kbA, vtA);
        rope_k<<<dim3(16384), 256, 0, stream>>>(qbA, kbA, tab);
        attn_k<<<dim3(1024), 256, 0, stream>>>(qbA, kbA, vtA, ybA);
        gemm2_proj_k<<<dim3(16, 32, 2), 256, 0, stream>>>(ybA, wtP, out);
        return;
    }

    // -------- fallback: R21 per-batch loop (same kernels, z=1 grids) ------
    ushort* qb  = (ushort*)d_ws;               // 4 MB bf16 q
    ushort* kb  = qb + PB;                     // 4 MB bf16 k
    ushort* vtb = kb + PB;                     // 4 MB bf16 v^T
    ushort* yb  = vtb + PB;                    // 4 MB bf16 y / x_bf16
    const bool hoistWp = ws_size >= (size_t)18 * 1024 * 1024;
    ushort* wtP_stable = yb + PB;              // d_ws + 16MB (only if hoistWp)

    tp_k<<<dim3(96, 32), 256, 0, stream>>>(Wa, wtA, 1024, 3072);
    trig_k<<<dim3(256), 256, 0, stream>>>(tab);
    if (hoistWp)
        tp_k<<<dim3(32, 32), 256, 0, stream>>>(Wp, wtP_stable, 1024, 1024);

    for (int b = 0; b < 2; b++) {
        cvt_k<<<dim3(2048), 256, 0, stream>>>(x + b * PB, yb);        // xb in yb slot
        gemm1_qkv_k<<<dim3(48, 16, 1), 256, 0, stream>>>(yb, wtA, qb, kb, vtb);
        rope_k<<<dim3(8192), 256, 0, stream>>>(qb, kb, tab);
        attn_k<<<dim3(512), 256, 0, stream>>>(qb, kb, vtb, yb);       // y over xb
        if (hoistWp) {
            gemm2_proj_k<<<dim3(16, 32, 1), 256, 0, stream>>>(yb, wtP_stable, out + b * PB);
        } else {
            tp_k<<<dim3(32, 32), 256, 0, stream>>>(Wp, qb, 1024, 1024);  // over dead q
            gemm2_proj_k<<<dim3(16, 32, 1), 256, 0, stream>>>(yb, qb, out + b * PB);
        }
    }
}

// Round 15
// 205.393 us; speedup vs baseline: 1.0470x; 1.0470x over previous
//
#include <hip/hip_runtime.h>

// ---------------------------------------------------------------------------
// qkv = x@W_attn; RoPE(q,k); flash-attn; y@W_proj
// B=2, T=2048, C=1024, H=16, HD=64.  I/O fp32; internal tensors bf16.
//
// R26 (R25 = NULL: attn (256,3) hint did not raise occupancy (21.7% both) —
// LDS 49KB/block won't triple-up; reverted all launch_bounds to R24 config.
// attn VALUBusy 50% / Mfma 12% -> cut the softmax VALU op count directly):
//  * attn mask-skip: wave-uniform `kbase+127 <= wrow0` skips the cmp+cndmask
//    pass on fully-causal tiles (~94% of tiles; the masked path is kept
//    whenever any lane could need it).
//  * attn exp2-domain softmax: scores scaled once by 0.125*log2(e) (exact
//    fold: x0.125 is an exponent shift), M/L tracked in scaled domain (max is
//    order-preserving), raw v_exp_f32 (2^x) via asm — drops __expf's internal
//    x*log2e mul.  Same HW transcendental, ~1ulp delta.
//  * attn P->bf16 via v_cvt_pk_bf16_f32 (T12 recipe): 16 packed converts
//    replace ~112 manual-RNE bit ops per tile.  RNE both ways.
//  * everything else byte-identical to measured R24 (212.36us).
// ---------------------------------------------------------------------------

typedef __attribute__((ext_vector_type(8))) short short8;   // 8 bf16 = 4 VGPRs
typedef __attribute__((ext_vector_type(4))) float floatx4;  // MFMA C/D frag

__device__ __forceinline__ ushort f2bf(float f) {
    unsigned x = __float_as_uint(f);
    x += 0x7fffu + ((x >> 16) & 1u);   // round-to-nearest-even
    return (ushort)(x >> 16);
}
__device__ __forceinline__ float bf2f(ushort u) {
    return __uint_as_float(((unsigned)u) << 16);
}
__device__ __forceinline__ float exp2fast(float x) {   // 2^x, raw v_exp_f32
    float r;
    asm("v_exp_f32 %0, %1" : "=v"(r) : "v"(x));
    return r;
}
__device__ __forceinline__ unsigned cvtpk_bf16(float lo, float hi) {
    unsigned r;                                        // [bf16(hi)|bf16(lo)]
    asm("v_cvt_pk_bf16_f32 %0, %1, %2" : "=v"(r) : "v"(lo), "v"(hi));
    return r;
}

#define MFMA16(a, b, c) __builtin_amdgcn_mfma_f32_16x16x32_bf16((a), (b), (c), 0, 0, 0)

// async global->LDS, 16 bytes per lane.  LDS dest must be wave-uniform base;
// HW writes base + lane*16.  Global src is per-lane.
__device__ __forceinline__ void glds16(const ushort* g, ushort* l) {
    __builtin_amdgcn_global_load_lds(
        (const __attribute__((address_space(1))) unsigned int*)g,
        (__attribute__((address_space(3))) unsigned int*)l, 16, 0, 0);
}

// ---------------------------------------------------------------------------
// Transpose + cvt: src f32 [R][C] -> dst bf16 [C][R].  32x32 tiles via LDS.
// ---------------------------------------------------------------------------
__global__ __launch_bounds__(256) void tp_k(const float* __restrict__ src,
                                            ushort* __restrict__ dst,
                                            int R, int C) {
    __shared__ ushort t[32][34];
    const int c0 = blockIdx.x * 32, r0 = blockIdx.y * 32;
    const int tr = threadIdx.x >> 5, tc = threadIdx.x & 31;
#pragma unroll
    for (int j = 0; j < 4; j++)
        t[tr + j * 8][tc] = f2bf(src[(size_t)(r0 + tr + j * 8) * C + c0 + tc]);
    __syncthreads();
#pragma unroll
    for (int j = 0; j < 4; j++)
        dst[(size_t)(c0 + tr + j * 8) * R + r0 + tc] = t[tc][tr + j * 8];
}

// ---------------------------------------------------------------------------
// cvt: f32 -> bf16, 4 elems/thread.
// ---------------------------------------------------------------------------
__global__ __launch_bounds__(256) void cvt_k(const float* __restrict__ src,
                                             ushort* __restrict__ dst) {
    const size_t i = ((size_t)blockIdx.x * 256 + threadIdx.x) * 4;
    float4 t4 = *(const float4*)&src[i];
    *(ushort4*)&dst[i] = make_ushort4(f2bf(t4.x), f2bf(t4.y), f2bf(t4.z), f2bf(t4.w));
}

// ---------------------------------------------------------------------------
// trig table: tab[t][j] = (cos(t * 10000^(-j/32)), sin(...)), f64 math
// identical to the original in-rope computation (bit-identical results).
// ---------------------------------------------------------------------------
__global__ __launch_bounds__(256) void trig_k(float2* __restrict__ tab) {
    const int idx = blockIdx.x * 256 + threadIdx.x;   // [0, 65536)
    const int t = idx >> 5, j = idx & 31;
    const double inv = pow(10000.0, -(double)j / 32.0);
    const double ang = (double)t * inv;
    tab[idx] = make_float2((float)cos(ang), (float)sin(ang));
}

// ---------------------------------------------------------------------------
// GEMM1: qkv = xb[2048][1024](bf16) @ WaT^T (Bt bf16 [3072][1024])
//   -> q: [H,T,HD]  k: [H,T,HD]  v^T: [H,HD,T]  (bf16)
// R15/R18 form (measured best): 128x64 tile, BK=64, glds16, swizzled LDS.
// R24: batch from blockIdx.z.
// ---------------------------------------------------------------------------
__global__ __launch_bounds__(256, 3) void gemm1_qkv_k(const ushort* __restrict__ Ab,
                                                      const ushort* __restrict__ Bt,
                                                      ushort* __restrict__ qb,
                                                      ushort* __restrict__ kb,
                                                      ushort* __restrict__ vtb) {
    __shared__ __align__(16) ushort As[128 * 64];  // 16 KB, linear+swizzled
    __shared__ __align__(16) ushort Bs[64 * 64];   // 8 KB
    const size_t boff = (size_t)blockIdx.z * (2048u * 1024u);
    Ab += boff; qb += boff; kb += boff; vtb += boff;
    const int tid = threadIdx.x;
    const int m0 = blockIdx.y * 128, n0 = blockIdx.x * 64;
    const int w = tid >> 6, lane = tid & 63, quad = lane >> 4, l16 = lane & 15;
    const int wr = w >> 1, wc = w & 1;
    const int K = 1024;
    const int srow = lane >> 3, sslot = lane & 7;  // staging sub-row / slot

    floatx4 acc[4][2];
#pragma unroll
    for (int mt = 0; mt < 4; mt++)
#pragma unroll
        for (int nt = 0; nt < 2; nt++) acc[mt][nt] = (floatx4){0.f, 0.f, 0.f, 0.f};

    for (int k0 = 0; k0 < K; k0 += 64) {
        __syncthreads();   // all waves done reading prev tile
#pragma unroll
        for (int jj = 0; jj < 4; jj++) {
            const int reg = jj * 4 + w;
            const int row = reg * 8 + srow;
            const int cs = sslot ^ (row & 7);
            glds16(&Ab[(size_t)(m0 + row) * K + k0 + cs * 8], &As[reg * 512]);
        }
#pragma unroll
        for (int jj = 0; jj < 2; jj++) {
            const int reg = jj * 4 + w;
            const int row = reg * 8 + srow;
            const int cs = sslot ^ (row & 7);
            glds16(&Bt[(size_t)(n0 + row) * K + k0 + cs * 8], &Bs[reg * 512]);
        }
        __syncthreads();   // compiler drains vmcnt(0) before barrier

#pragma unroll
        for (int kk = 0; kk < 2; kk++) {
            short8 af[4], bfr[2];
#pragma unroll
            for (int mt = 0; mt < 4; mt++) {
                const int row = wr * 64 + mt * 16 + l16;
                const int slot = ((kk << 2) | quad) ^ (row & 7);
                af[mt] = *(short8*)&As[row * 64 + slot * 8];
            }
#pragma unroll
            for (int nt = 0; nt < 2; nt++) {
                const int row = wc * 32 + nt * 16 + l16;
                const int slot = ((kk << 2) | quad) ^ (row & 7);
                bfr[nt] = *(short8*)&Bs[row * 64 + slot * 8];
            }
#pragma unroll
            for (int mt = 0; mt < 4; mt++)
#pragma unroll
                for (int nt = 0; nt < 2; nt++) acc[mt][nt] = MFMA16(af[mt], bfr[nt], acc[mt][nt]);
        }
    }

    // Epilogue [R5-R10 verified formulas; nt bound 2, wave n-stride 32]
#pragma unroll
    for (int nt = 0; nt < 2; nt++) {
        const int n = n0 + wc * 32 + nt * 16 + l16;
        const int seg = n >> 10;          // 0=q 1=k 2=v
        const int cn = n & 1023;
        const int h = cn >> 6, d = cn & 63;
#pragma unroll
        for (int mt = 0; mt < 4; mt++) {
#pragma unroll
            for (int r = 0; r < 4; r++) {
                const int t = m0 + wr * 64 + mt * 16 + quad * 4 + r;
                const ushort v = f2bf(acc[mt][nt][r]);
                if (seg == 0)      qb[((size_t)h * 2048 + t) * 64 + d] = v;
                else if (seg == 1) kb[((size_t)h * 2048 + t) * 64 + d] = v;
                else               vtb[((size_t)h * 64 + d) * 2048 + t] = v;
            }
        }
    }
}

// ---------------------------------------------------------------------------
// RoPE (roll variant), table-based trig.  Math identical to verified R5-R11.
// Row index spans batches naturally (row = (b*16+h)*2048 + t; t = wid&2047).
// ---------------------------------------------------------------------------
__global__ __launch_bounds__(256) void rope_k(ushort* __restrict__ q,
                                              ushort* __restrict__ k,
                                              const float2* __restrict__ tab) {
    const int wid = blockIdx.x * 4 + (threadIdx.x >> 6);  // row
    const int lane = threadIdx.x & 63;
    const int t = wid & 2047;
    const float2 cs = tab[t * 32 + (lane & 31)];
    const float c = cs.x;
    const float s = cs.y;
    const size_t base = (size_t)wid * 64;

    float qv = bf2f(q[base + lane]);
    float qp = __shfl(qv, (lane + 63) & 63, 64);
    q[base + lane] = f2bf(qv * c + qp * s);

    float kv = bf2f(k[base + lane]);
    float kp = __shfl(kv, (lane + 63) & 63, 64);
    k[base + lane] = f2bf(kv * c + kp * s);
}

// ---------------------------------------------------------------------------
// Flash attention (causal), transposed form.
// R12: one q-tile per block.  R13: no Ps barrier.  R14: balanced qt remap.
// R21: KVBLK=128 + glds16 staging + exact-skip defer-max + setprio.
// R24: batch = bid>>9 (grid 1024 merged / 512 fallback).
// R26: mask-skip on fully-causal tiles; exp2-domain softmax (scale folded
//      with log2e — exact since x0.125 is an exponent shift); P->bf16 via
//      v_cvt_pk_bf16_f32.
// ---------------------------------------------------------------------------
__global__ __launch_bounds__(256, 2) void attn_k(const ushort* __restrict__ q,
                                                 const ushort* __restrict__ k,
                                                 const ushort* __restrict__ vt,
                                                 ushort* __restrict__ y) {
    __shared__ __align__(16) ushort Ks[128 * 64];   // [key][d]  16 KB swz
    __shared__ __align__(16) ushort Vs[64 * 128];   // [d][key]  16 KB swz
    __shared__ __align__(16) ushort Ps[4][16][136]; // per-wave P^T [qrow][key]

    const int bid = blockIdx.x;
    const int b = bid >> 9;            // batch (0 under fallback grid 512)
    const int r9 = bid & 511;
    // r9 0..255: qt = 31,30,..,16 (16 heads each); 256..511: qt = 0,1,..,15
    const int qt = (r9 < 256) ? (31 - (r9 >> 4)) : ((r9 >> 4) - 16);
    const int h = r9 & 15;
    const size_t boff = (size_t)b * (2048u * 1024u);
    q += boff; k += boff; vt += boff; y += boff;
    const int tid = threadIdx.x, w = tid >> 6, lane = tid & 63;
    const int quad = lane >> 4, l16 = lane & 15;
    const int srow8 = lane >> 3, sslot8 = lane & 7;   // K staging (8 rows/KB)
    const int srow4 = lane >> 4, sslot16 = lane & 15; // V staging (4 rows/KB)

    const int q0 = qt * 64;
    const int qrow = q0 + w * 16 + l16;
    const int wrow0 = q0 + w * 16;     // min qrow in this wave
    const int nkt = (qt >> 1) + 1;     // 128-key tiles; trailing keys masked
    const float SC = 0.125f * 1.44269504f;  // score scale folded with log2(e)

    short8 qa0, qa1;
    {
        const ushort* qp = q + ((size_t)h * 2048 + qrow) * 64 + quad * 8;
        qa0 = *(const short8*)(qp);
        qa1 = *(const short8*)(qp + 32);
    }

    floatx4 O[4];
#pragma unroll
    for (int dt = 0; dt < 4; dt++) O[dt] = (floatx4){0.f, 0.f, 0.f, 0.f};
    float M = -30000.f, L = 0.f;

    for (int kt2 = 0; kt2 < nkt; kt2++) {
        const int kbase = kt2 * 128;
        __syncthreads();   // all waves done reading prev tile's LDS
        // K: 128 rows x 64 (128B rows, 8 chunks), 16 regions of 8 rows.
#pragma unroll
        for (int jj = 0; jj < 4; jj++) {
            const int reg = jj * 4 + w;
            const int row = reg * 8 + srow8;
            const int cs = sslot8 ^ (row & 7);
            glds16(&k[((size_t)h * 2048 + kbase + row) * 64 + cs * 8], &Ks[reg * 512]);
        }
        // V^T: 64 rows x 128 (256B rows, 16 chunks), 16 regions of 4 rows.
#pragma unroll
        for (int jj = 0; jj < 4; jj++) {
            const int reg = jj * 4 + w;
            const int row = reg * 4 + srow4;
            const int cs = sslot16 ^ (row & 15);
            glds16(&vt[((size_t)h * 64 + row) * 2048 + kbase + cs * 8], &Vs[reg * 512]);
        }
        __syncthreads();   // staging complete (vmcnt(0) drained at barrier)

        floatx4 s[8];
        __builtin_amdgcn_s_setprio(1);   // T5: QK^T MFMA cluster
#pragma unroll
        for (int nt = 0; nt < 8; nt++) {
            const int row = nt * 16 + l16;
            short8 ka0 = *(short8*)&Ks[row * 64 + ((quad ^ (row & 7)) * 8)];
            short8 ka1 = *(short8*)&Ks[row * 64 + (((4 | quad) ^ (row & 7)) * 8)];
            floatx4 z = (floatx4){0.f, 0.f, 0.f, 0.f};
            z = MFMA16(ka0, qa0, z);
            z = MFMA16(ka1, qa1, z);
            s[nt] = z;
        }
        __builtin_amdgcn_s_setprio(0);

        // scale (+ causal mask only when this wave's rows can be masked)
        if (kbase + 127 <= wrow0) {
#pragma unroll
            for (int nt = 0; nt < 8; nt++)
#pragma unroll
                for (int r = 0; r < 4; r++) s[nt][r] *= SC;
        } else {
#pragma unroll
            for (int nt = 0; nt < 8; nt++)
#pragma unroll
                for (int r = 0; r < 4; r++) {
                    const int kidx = kbase + nt * 16 + quad * 4 + r;
                    const float vv = s[nt][r] * SC;
                    s[nt][r] = (kidx > qrow) ? -30000.f : vv;
                }
        }

        // tree max over 32 values (max is exactly associative)
        float mr[8];
#pragma unroll
        for (int nt = 0; nt < 8; nt++)
            mr[nt] = fmaxf(fmaxf(s[nt][0], s[nt][1]), fmaxf(s[nt][2], s[nt][3]));
        float mx = fmaxf(fmaxf(fmaxf(mr[0], mr[1]), fmaxf(mr[2], mr[3])),
                         fmaxf(fmaxf(mr[4], mr[5]), fmaxf(mr[6], mr[7])));
        mx = fmaxf(mx, __shfl_xor(mx, 16, 64));
        mx = fmaxf(mx, __shfl_xor(mx, 32, 64));

        // exact-skip defer-max: if no lane's max grew, Mn==M and alpha==1
        // exactly -> skipping rescale is bit-identical.
        if (!__all(mx <= M)) {
            const float Mn = fmaxf(M, mx);
            const float alpha = exp2fast(M - Mn);
            L *= alpha;
#pragma unroll
            for (int dt = 0; dt < 4; dt++) O[dt] *= alpha;
            M = Mn;
        }

        float sum = 0.f;
#pragma unroll
        for (int nt = 0; nt < 8; nt++)
#pragma unroll
            for (int r = 0; r < 4; r++) {
                const float pv = exp2fast(s[nt][r] - M);
                s[nt][r] = pv;
                sum += pv;
            }
        sum += __shfl_xor(sum, 16, 64);
        sum += __shfl_xor(sum, 32, 64);
        L += sum;

#pragma unroll
        for (int nt = 0; nt < 8; nt++) {
            uint2 pk2;
            pk2.x = cvtpk_bf16(s[nt][0], s[nt][1]);
            pk2.y = cvtpk_bf16(s[nt][2], s[nt][3]);
            *(uint2*)&Ps[w][l16][nt * 16 + quad * 4] = pk2;
        }
        // no barrier: Ps[w] is written and read only by wave w; in-wave DS
        // ordering is enforced by the compiler's lgkmcnt tracking.

        short8 pb[4];
#pragma unroll
        for (int ks = 0; ks < 4; ks++)
            pb[ks] = *(short8*)&Ps[w][l16][ks * 32 + quad * 8];
        __builtin_amdgcn_s_setprio(1);   // T5: PV MFMA cluster
#pragma unroll
        for (int dt = 0; dt < 4; dt++) {
            const int row = dt * 16 + l16;
#pragma unroll
            for (int ks = 0; ks < 4; ks++) {
                const int cc = (ks * 4 + quad) ^ (row & 15);
                short8 va = *(short8*)&Vs[row * 128 + cc * 8];
                O[dt] = MFMA16(va, pb[ks], O[dt]);
            }
        }
        __builtin_amdgcn_s_setprio(0);
    }

    const float rl = 1.0f / L;
#pragma unroll
    for (int dt = 0; dt < 4; dt++) {
        ushort4 o4 = make_ushort4(f2bf(O[dt][0] * rl), f2bf(O[dt][1] * rl),
                                  f2bf(O[dt][2] * rl), f2bf(O[dt][3] * rl));
        *(ushort4*)&y[(size_t)qrow * 1024 + h * 64 + dt * 16 + quad * 4] = o4;
    }
}

// ---------------------------------------------------------------------------
// GEMM2: out(f32) = y[2048][1024](bf16) @ WpT^T (bf16 [1024][1024])
// R15/R18 form (measured best): 64x64 tile, BK=64, glds16, swizzled LDS.
// R24: batch from blockIdx.z.
// ---------------------------------------------------------------------------
__global__ __launch_bounds__(256, 2) void gemm2_proj_k(const ushort* __restrict__ Y,
                                                       const ushort* __restrict__ Bt,
                                                       float* __restrict__ out) {
    __shared__ __align__(16) ushort As[64 * 64];   // 8 KB, linear+swizzled
    __shared__ __align__(16) ushort Bs[64 * 64];   // 8 KB
    const size_t boff = (size_t)blockIdx.z * (2048u * 1024u);
    Y += boff; out += boff;
    const int tid = threadIdx.x;
    const int m0 = blockIdx.y * 64, n0 = blockIdx.x * 64;
    const int w = tid >> 6, lane = tid & 63, quad = lane >> 4, l16 = lane & 15;
    const int wr = w >> 1, wc = w & 1;
    const int K = 1024;
    const int srow = lane >> 3, sslot = lane & 7;

    floatx4 acc[2][2];
#pragma unroll
    for (int mt = 0; mt < 2; mt++)
#pragma unroll
        for (int nt = 0; nt < 2; nt++) acc[mt][nt] = (floatx4){0.f, 0.f, 0.f, 0.f};

    for (int k0 = 0; k0 < K; k0 += 64) {
        __syncthreads();
#pragma unroll
        for (int jj = 0; jj < 2; jj++) {
            const int reg = jj * 4 + w;
            const int row = reg * 8 + srow;
            const int cs = sslot ^ (row & 7);
            glds16(&Y[(size_t)(m0 + row) * K + k0 + cs * 8], &As[reg * 512]);
            glds16(&Bt[(size_t)(n0 + row) * K + k0 + cs * 8], &Bs[reg * 512]);
        }
        __syncthreads();

#pragma unroll
        for (int kk = 0; kk < 2; kk++) {
            short8 af[2], bfr[2];
#pragma unroll
            for (int mt = 0; mt < 2; mt++) {
                const int row = wr * 32 + mt * 16 + l16;
                const int slot = ((kk << 2) | quad) ^ (row & 7);
                af[mt] = *(short8*)&As[row * 64 + slot * 8];
            }
#pragma unroll
            for (int nt = 0; nt < 2; nt++) {
                const int row = wc * 32 + nt * 16 + l16;
                const int slot = ((kk << 2) | quad) ^ (row & 7);
                bfr[nt] = *(short8*)&Bs[row * 64 + slot * 8];
            }
#pragma unroll
            for (int mt = 0; mt < 2; mt++)
#pragma unroll
                for (int nt = 0; nt < 2; nt++) acc[mt][nt] = MFMA16(af[mt], bfr[nt], acc[mt][nt]);
        }
    }

#pragma unroll
    for (int mt = 0; mt < 2; mt++)
#pragma unroll
        for (int nt = 0; nt < 2; nt++) {
            const int n = n0 + wc * 32 + nt * 16 + l16;
#pragma unroll
            for (int r = 0; r < 4; r++) {
                const int m = m0 + wr * 32 + mt * 16 + quad * 4 + r;
                out[(size_t)m * 1024 + n] = acc[mt][nt][r];
            }
        }
}

// ---------------------------------------------------------------------------
extern "C" void kernel_launch(void* const* d_in, const int* in_sizes, int n_in,
                              void* d_out, int out_size, void* d_ws, size_t ws_size,
                              hipStream_t stream) {
    const float* x  = (const float*)d_in[0];   // [2,2048,1024] f32
    const float* Wa = (const float*)d_in[1];   // [1024,3072]  f32
    const float* Wp = (const float*)d_in[2];   // [1024,1024]  f32
    float* out = (float*)d_out;                // [2,2048,1024] f32

    const size_t PB = (size_t)2048 * 1024;     // per-batch elements
    ushort* wtA = (ushort*)(out + PB);         // 6 MB W_attn^T bf16 (d_out b1
                                               //  half; dead after gemm1, and
                                               //  gemm2-b1 fully overwrites it)
    float2* tab = (float2*)(wtA + (size_t)3 * 1024 * 1024);
                                               // 512 KB trig table (d_out b1
                                               //  tail; dead after rope)

    if (ws_size >= (size_t)36 * 1024 * 1024) {
        // -------- merged-batch path: 8 launches ---------------------------
        ushort* qbA = (ushort*)d_ws;           // [2] x 4 MB  q  [b][H,T,HD]
        ushort* kbA = qbA + 2 * PB;            // [2] x 4 MB  k
        ushort* vtA = qbA + 4 * PB;            // [2] x 4 MB  v^T
        ushort* ybA = qbA + 6 * PB;            // [2] x 4 MB  x_bf16 / y
        ushort* wtP = qbA + 8 * PB;            // 2 MB  W_proj^T

        tp_k<<<dim3(96, 32), 256, 0, stream>>>(Wa, wtA, 1024, 3072);
        trig_k<<<dim3(256), 256, 0, stream>>>(tab);
        tp_k<<<dim3(32, 32), 256, 0, stream>>>(Wp, wtP, 1024, 1024);

        cvt_k<<<dim3(4096), 256, 0, stream>>>(x, ybA);
        gemm1_qkv_k<<<dim3(48, 16, 2), 256, 0, stream>>>(ybA, wtA, qbA, kbA, vtA);
        rope_k<<<dim3(16384), 256, 0, stream>>>(qbA, kbA, tab);
        attn_k<<<dim3(1024), 256, 0, stream>>>(qbA, kbA, vtA, ybA);
        gemm2_proj_k<<<dim3(16, 32, 2), 256, 0, stream>>>(ybA, wtP, out);
        return;
    }

    // -------- fallback: per-batch loop (same kernels, z=1 grids) ----------
    ushort* qb  = (ushort*)d_ws;               // 4 MB bf16 q
    ushort* kb  = qb + PB;                     // 4 MB bf16 k
    ushort* vtb = kb + PB;                     // 4 MB bf16 v^T
    ushort* yb  = vtb + PB;                    // 4 MB bf16 y / x_bf16
    const bool hoistWp = ws_size >= (size_t)18 * 1024 * 1024;
    ushort* wtP_stable = yb + PB;              // d_ws + 16MB (only if hoistWp)

    tp_k<<<dim3(96, 32), 256, 0, stream>>>(Wa, wtA, 1024, 3072);
    trig_k<<<dim3(256), 256, 0, stream>>>(tab);
    if (hoistWp)
        tp_k<<<dim3(32, 32), 256, 0, stream>>>(Wp, wtP_stable, 1024, 1024);

    for (int b = 0; b < 2; b++) {
        cvt_k<<<dim3(2048), 256, 0, stream>>>(x + b * PB, yb);        // xb in yb slot
        gemm1_qkv_k<<<dim3(48, 16, 1), 256, 0, stream>>>(yb, wtA, qb, kb, vtb);
        rope_k<<<dim3(8192), 256, 0, stream>>>(qb, kb, tab);
        attn_k<<<dim3(512), 256, 0, stream>>>(qb, kb, vtb, yb);       // y over xb
        if (hoistWp) {
            gemm2_proj_k<<<dim3(16, 32, 1), 256, 0, stream>>>(yb, wtP_stable, out + b * PB);
        } else {
            tp_k<<<dim3(32, 32), 256, 0, stream>>>(Wp, qb, 1024, 1024);  // over dead q
            gemm2_proj_k<<<dim3(16, 32, 1), 256, 0, stream>>>(yb, qb, out + b * PB);
        }
    }
}

// Round 17
// 204.073 us; speedup vs baseline: 1.0537x; 1.0065x over previous
//
#include <hip/hip_runtime.h>

// ---------------------------------------------------------------------------
// qkv = x@W_attn; RoPE(q,k); flash-attn; y@W_proj
// B=2, T=2048, C=1024, H=16, HD=64.  I/O fp32; internal tensors bf16.
//
// R28 == R27 byte-identical (infra "container failed twice"; R27 unmeasured).
// Audited this round: staging coverage/bounds exact, no new sync (no hang
// mode), ~115 VGPR < 170 cap, LDS 96/160 KB at 3 blocks/CU, epilogue is the
// R5-R14-verified 128x128 form.  Submitting unchanged.
//
// R27 change log (vs measured R26 = 205.39us):
//  * gemm1 tile 128x64 -> 128x128: merged-batch grid 24x16x2 = 768 blocks =
//    still 3/CU, 2x MFMA per staging byte, half the B-panel traffic.
//  * everything else byte-identical to measured R26 (attn mask-skip/exp2/
//    cvt_pk, merged launches, R18-form gemm2).
// ---------------------------------------------------------------------------

typedef __attribute__((ext_vector_type(8))) short short8;   // 8 bf16 = 4 VGPRs
typedef __attribute__((ext_vector_type(4))) float floatx4;  // MFMA C/D frag

__device__ __forceinline__ ushort f2bf(float f) {
    unsigned x = __float_as_uint(f);
    x += 0x7fffu + ((x >> 16) & 1u);   // round-to-nearest-even
    return (ushort)(x >> 16);
}
__device__ __forceinline__ float bf2f(ushort u) {
    return __uint_as_float(((unsigned)u) << 16);
}
__device__ __forceinline__ float exp2fast(float x) {   // 2^x, raw v_exp_f32
    float r;
    asm("v_exp_f32 %0, %1" : "=v"(r) : "v"(x));
    return r;
}
__device__ __forceinline__ unsigned cvtpk_bf16(float lo, float hi) {
    unsigned r;                                        // [bf16(hi)|bf16(lo)]
    asm("v_cvt_pk_bf16_f32 %0, %1, %2" : "=v"(r) : "v"(lo), "v"(hi));
    return r;
}

#define MFMA16(a, b, c) __builtin_amdgcn_mfma_f32_16x16x32_bf16((a), (b), (c), 0, 0, 0)

// async global->LDS, 16 bytes per lane.  LDS dest must be wave-uniform base;
// HW writes base + lane*16.  Global src is per-lane.
__device__ __forceinline__ void glds16(const ushort* g, ushort* l) {
    __builtin_amdgcn_global_load_lds(
        (const __attribute__((address_space(1))) unsigned int*)g,
        (__attribute__((address_space(3))) unsigned int*)l, 16, 0, 0);
}

// ---------------------------------------------------------------------------
// Transpose + cvt: src f32 [R][C] -> dst bf16 [C][R].  32x32 tiles via LDS.
// ---------------------------------------------------------------------------
__global__ __launch_bounds__(256) void tp_k(const float* __restrict__ src,
                                            ushort* __restrict__ dst,
                                            int R, int C) {
    __shared__ ushort t[32][34];
    const int c0 = blockIdx.x * 32, r0 = blockIdx.y * 32;
    const int tr = threadIdx.x >> 5, tc = threadIdx.x & 31;
#pragma unroll
    for (int j = 0; j < 4; j++)
        t[tr + j * 8][tc] = f2bf(src[(size_t)(r0 + tr + j * 8) * C + c0 + tc]);
    __syncthreads();
#pragma unroll
    for (int j = 0; j < 4; j++)
        dst[(size_t)(c0 + tr + j * 8) * R + r0 + tc] = t[tc][tr + j * 8];
}

// ---------------------------------------------------------------------------
// cvt: f32 -> bf16, 4 elems/thread.
// ---------------------------------------------------------------------------
__global__ __launch_bounds__(256) void cvt_k(const float* __restrict__ src,
                                             ushort* __restrict__ dst) {
    const size_t i = ((size_t)blockIdx.x * 256 + threadIdx.x) * 4;
    float4 t4 = *(const float4*)&src[i];
    *(ushort4*)&dst[i] = make_ushort4(f2bf(t4.x), f2bf(t4.y), f2bf(t4.z), f2bf(t4.w));
}

// ---------------------------------------------------------------------------
// trig table: tab[t][j] = (cos(t * 10000^(-j/32)), sin(...)), f64 math
// identical to the original in-rope computation (bit-identical results).
// ---------------------------------------------------------------------------
__global__ __launch_bounds__(256) void trig_k(float2* __restrict__ tab) {
    const int idx = blockIdx.x * 256 + threadIdx.x;   // [0, 65536)
    const int t = idx >> 5, j = idx & 31;
    const double inv = pow(10000.0, -(double)j / 32.0);
    const double ang = (double)t * inv;
    tab[idx] = make_float2((float)cos(ang), (float)sin(ang));
}

// ---------------------------------------------------------------------------
// GEMM1: qkv = xb[2048][1024](bf16) @ WaT^T (Bt bf16 [3072][1024])
//   -> q: [H,T,HD]  k: [H,T,HD]  v^T: [H,HD,T]  (bf16)
// R27: 128x128 tile (grid 24x16xZ = 768 blocks merged = 3/CU), BK=64,
// glds16 staging, swizzled LDS.  Epilogue = R5-R14-verified 128x128 form.
// ---------------------------------------------------------------------------
__global__ __launch_bounds__(256, 3) void gemm1_qkv_k(const ushort* __restrict__ Ab,
                                                      const ushort* __restrict__ Bt,
                                                      ushort* __restrict__ qb,
                                                      ushort* __restrict__ kb,
                                                      ushort* __restrict__ vtb) {
    __shared__ __align__(16) ushort As[128 * 64];  // 16 KB, linear+swizzled
    __shared__ __align__(16) ushort Bs[128 * 64];  // 16 KB
    const size_t boff = (size_t)blockIdx.z * (2048u * 1024u);
    Ab += boff; qb += boff; kb += boff; vtb += boff;
    const int tid = threadIdx.x;
    const int m0 = blockIdx.y * 128, n0 = blockIdx.x * 128;
    const int w = tid >> 6, lane = tid & 63, quad = lane >> 4, l16 = lane & 15;
    const int wr = w >> 1, wc = w & 1;
    const int K = 1024;
    const int srow = lane >> 3, sslot = lane & 7;  // staging sub-row / slot

    floatx4 acc[4][4];
#pragma unroll
    for (int mt = 0; mt < 4; mt++)
#pragma unroll
        for (int nt = 0; nt < 4; nt++) acc[mt][nt] = (floatx4){0.f, 0.f, 0.f, 0.f};

    for (int k0 = 0; k0 < K; k0 += 64) {
        __syncthreads();   // all waves done reading prev tile
#pragma unroll
        for (int jj = 0; jj < 4; jj++) {
            const int reg = jj * 4 + w;
            const int row = reg * 8 + srow;
            const int cs = sslot ^ (row & 7);
            glds16(&Ab[(size_t)(m0 + row) * K + k0 + cs * 8], &As[reg * 512]);
        }
#pragma unroll
        for (int jj = 0; jj < 4; jj++) {
            const int reg = jj * 4 + w;
            const int row = reg * 8 + srow;
            const int cs = sslot ^ (row & 7);
            glds16(&Bt[(size_t)(n0 + row) * K + k0 + cs * 8], &Bs[reg * 512]);
        }
        __syncthreads();   // compiler drains vmcnt(0) before barrier

#pragma unroll
        for (int kk = 0; kk < 2; kk++) {
            short8 af[4], bfr[4];
#pragma unroll
            for (int mt = 0; mt < 4; mt++) {
                const int row = wr * 64 + mt * 16 + l16;
                const int slot = ((kk << 2) | quad) ^ (row & 7);
                af[mt] = *(short8*)&As[row * 64 + slot * 8];
            }
#pragma unroll
            for (int nt = 0; nt < 4; nt++) {
                const int row = wc * 64 + nt * 16 + l16;
                const int slot = ((kk << 2) | quad) ^ (row & 7);
                bfr[nt] = *(short8*)&Bs[row * 64 + slot * 8];
            }
#pragma unroll
            for (int mt = 0; mt < 4; mt++)
#pragma unroll
                for (int nt = 0; nt < 4; nt++) acc[mt][nt] = MFMA16(af[mt], bfr[nt], acc[mt][nt]);
        }
    }

    // Epilogue [R5-R14 verified 128x128 formulas]
#pragma unroll
    for (int nt = 0; nt < 4; nt++) {
        const int n = n0 + wc * 64 + nt * 16 + l16;
        const int seg = n >> 10;          // 0=q 1=k 2=v
        const int cn = n & 1023;
        const int h = cn >> 6, d = cn & 63;
#pragma unroll
        for (int mt = 0; mt < 4; mt++) {
#pragma unroll
            for (int r = 0; r < 4; r++) {
                const int t = m0 + wr * 64 + mt * 16 + quad * 4 + r;
                const ushort v = f2bf(acc[mt][nt][r]);
                if (seg == 0)      qb[((size_t)h * 2048 + t) * 64 + d] = v;
                else if (seg == 1) kb[((size_t)h * 2048 + t) * 64 + d] = v;
                else               vtb[((size_t)h * 64 + d) * 2048 + t] = v;
            }
        }
    }
}

// ---------------------------------------------------------------------------
// RoPE (roll variant), table-based trig.  Math identical to verified R5-R11.
// Row index spans batches naturally (row = (b*16+h)*2048 + t; t = wid&2047).
// ---------------------------------------------------------------------------
__global__ __launch_bounds__(256) void rope_k(ushort* __restrict__ q,
                                              ushort* __restrict__ k,
                                              const float2* __restrict__ tab) {
    const int wid = blockIdx.x * 4 + (threadIdx.x >> 6);  // row
    const int lane = threadIdx.x & 63;
    const int t = wid & 2047;
    const float2 cs = tab[t * 32 + (lane & 31)];
    const float c = cs.x;
    const float s = cs.y;
    const size_t base = (size_t)wid * 64;

    float qv = bf2f(q[base + lane]);
    float qp = __shfl(qv, (lane + 63) & 63, 64);
    q[base + lane] = f2bf(qv * c + qp * s);

    float kv = bf2f(k[base + lane]);
    float kp = __shfl(kv, (lane + 63) & 63, 64);
    k[base + lane] = f2bf(kv * c + kp * s);
}

// ---------------------------------------------------------------------------
// Flash attention (causal), transposed form.
// R12: one q-tile per block.  R13: no Ps barrier.  R14: balanced qt remap.
// R21: KVBLK=128 + glds16 staging + exact-skip defer-max + setprio.
// R24: batch = bid>>9.  R26: mask-skip, exp2-domain softmax, cvt_pk P->bf16.
// ---------------------------------------------------------------------------
__global__ __launch_bounds__(256, 2) void attn_k(const ushort* __restrict__ q,
                                                 const ushort* __restrict__ k,
                                                 const ushort* __restrict__ vt,
                                                 ushort* __restrict__ y) {
    __shared__ __align__(16) ushort Ks[128 * 64];   // [key][d]  16 KB swz
    __shared__ __align__(16) ushort Vs[64 * 128];   // [d][key]  16 KB swz
    __shared__ __align__(16) ushort Ps[4][16][136]; // per-wave P^T [qrow][key]

    const int bid = blockIdx.x;
    const int b = bid >> 9;            // batch (0 under fallback grid 512)
    const int r9 = bid & 511;
    // r9 0..255: qt = 31,30,..,16 (16 heads each); 256..511: qt = 0,1,..,15
    const int qt = (r9 < 256) ? (31 - (r9 >> 4)) : ((r9 >> 4) - 16);
    const int h = r9 & 15;
    const size_t boff = (size_t)b * (2048u * 1024u);
    q += boff; k += boff; vt += boff; y += boff;
    const int tid = threadIdx.x, w = tid >> 6, lane = tid & 63;
    const int quad = lane >> 4, l16 = lane & 15;
    const int srow8 = lane >> 3, sslot8 = lane & 7;   // K staging (8 rows/KB)
    const int srow4 = lane >> 4, sslot16 = lane & 15; // V staging (4 rows/KB)

    const int q0 = qt * 64;
    const int qrow = q0 + w * 16 + l16;
    const int wrow0 = q0 + w * 16;     // min qrow in this wave
    const int nkt = (qt >> 1) + 1;     // 128-key tiles; trailing keys masked
    const float SC = 0.125f * 1.44269504f;  // score scale folded with log2(e)

    short8 qa0, qa1;
    {
        const ushort* qp = q + ((size_t)h * 2048 + qrow) * 64 + quad * 8;
        qa0 = *(const short8*)(qp);
        qa1 = *(const short8*)(qp + 32);
    }

    floatx4 O[4];
#pragma unroll
    for (int dt = 0; dt < 4; dt++) O[dt] = (floatx4){0.f, 0.f, 0.f, 0.f};
    float M = -30000.f, L = 0.f;

    for (int kt2 = 0; kt2 < nkt; kt2++) {
        const int kbase = kt2 * 128;
        __syncthreads();   // all waves done reading prev tile's LDS
        // K: 128 rows x 64 (128B rows, 8 chunks), 16 regions of 8 rows.
#pragma unroll
        for (int jj = 0; jj < 4; jj++) {
            const int reg = jj * 4 + w;
            const int row = reg * 8 + srow8;
            const int cs = sslot8 ^ (row & 7);
            glds16(&k[((size_t)h * 2048 + kbase + row) * 64 + cs * 8], &Ks[reg * 512]);
        }
        // V^T: 64 rows x 128 (256B rows, 16 chunks), 16 regions of 4 rows.
#pragma unroll
        for (int jj = 0; jj < 4; jj++) {
            const int reg = jj * 4 + w;
            const int row = reg * 4 + srow4;
            const int cs = sslot16 ^ (row & 15);
            glds16(&vt[((size_t)h * 64 + row) * 2048 + kbase + cs * 8], &Vs[reg * 512]);
        }
        __syncthreads();   // staging complete (vmcnt(0) drained at barrier)

        floatx4 s[8];
        __builtin_amdgcn_s_setprio(1);   // T5: QK^T MFMA cluster
#pragma unroll
        for (int nt = 0; nt < 8; nt++) {
            const int row = nt * 16 + l16;
            short8 ka0 = *(short8*)&Ks[row * 64 + ((quad ^ (row & 7)) * 8)];
            short8 ka1 = *(short8*)&Ks[row * 64 + (((4 | quad) ^ (row & 7)) * 8)];
            floatx4 z = (floatx4){0.f, 0.f, 0.f, 0.f};
            z = MFMA16(ka0, qa0, z);
            z = MFMA16(ka1, qa1, z);
            s[nt] = z;
        }
        __builtin_amdgcn_s_setprio(0);

        // scale (+ causal mask only when this wave's rows can be masked)
        if (kbase + 127 <= wrow0) {
#pragma unroll
            for (int nt = 0; nt < 8; nt++)
#pragma unroll
                for (int r = 0; r < 4; r++) s[nt][r] *= SC;
        } else {
#pragma unroll
            for (int nt = 0; nt < 8; nt++)
#pragma unroll
                for (int r = 0; r < 4; r++) {
                    const int kidx = kbase + nt * 16 + quad * 4 + r;
                    const float vv = s[nt][r] * SC;
                    s[nt][r] = (kidx > qrow) ? -30000.f : vv;
                }
        }

        // tree max over 32 values (max is exactly associative)
        float mr[8];
#pragma unroll
        for (int nt = 0; nt < 8; nt++)
            mr[nt] = fmaxf(fmaxf(s[nt][0], s[nt][1]), fmaxf(s[nt][2], s[nt][3]));
        float mx = fmaxf(fmaxf(fmaxf(mr[0], mr[1]), fmaxf(mr[2], mr[3])),
                         fmaxf(fmaxf(mr[4], mr[5]), fmaxf(mr[6], mr[7])));
        mx = fmaxf(mx, __shfl_xor(mx, 16, 64));
        mx = fmaxf(mx, __shfl_xor(mx, 32, 64));

        // exact-skip defer-max: if no lane's max grew, Mn==M and alpha==1
        // exactly -> skipping rescale is bit-identical.
        if (!__all(mx <= M)) {
            const float Mn = fmaxf(M, mx);
            const float alpha = exp2fast(M - Mn);
            L *= alpha;
#pragma unroll
            for (int dt = 0; dt < 4; dt++) O[dt] *= alpha;
            M = Mn;
        }

        float sum = 0.f;
#pragma unroll
        for (int nt = 0; nt < 8; nt++)
#pragma unroll
            for (int r = 0; r < 4; r++) {
                const float pv = exp2fast(s[nt][r] - M);
                s[nt][r] = pv;
                sum += pv;
            }
        sum += __shfl_xor(sum, 16, 64);
        sum += __shfl_xor(sum, 32, 64);
        L += sum;

#pragma unroll
        for (int nt = 0; nt < 8; nt++) {
            uint2 pk2;
            pk2.x = cvtpk_bf16(s[nt][0], s[nt][1]);
            pk2.y = cvtpk_bf16(s[nt][2], s[nt][3]);
            *(uint2*)&Ps[w][l16][nt * 16 + quad * 4] = pk2;
        }
        // no barrier: Ps[w] is written and read only by wave w; in-wave DS
        // ordering is enforced by the compiler's lgkmcnt tracking.

        short8 pb[4];
#pragma unroll
        for (int ks = 0; ks < 4; ks++)
            pb[ks] = *(short8*)&Ps[w][l16][ks * 32 + quad * 8];
        __builtin_amdgcn_s_setprio(1);   // T5: PV MFMA cluster
#pragma unroll
        for (int dt = 0; dt < 4; dt++) {
            const int row = dt * 16 + l16;
#pragma unroll
            for (int ks = 0; ks < 4; ks++) {
                const int cc = (ks * 4 + quad) ^ (row & 15);
                short8 va = *(short8*)&Vs[row * 128 + cc * 8];
                O[dt] = MFMA16(va, pb[ks], O[dt]);
            }
        }
        __builtin_amdgcn_s_setprio(0);
    }

    const float rl = 1.0f / L;
#pragma unroll
    for (int dt = 0; dt < 4; dt++) {
        ushort4 o4 = make_ushort4(f2bf(O[dt][0] * rl), f2bf(O[dt][1] * rl),
                                  f2bf(O[dt][2] * rl), f2bf(O[dt][3] * rl));
        *(ushort4*)&y[(size_t)qrow * 1024 + h * 64 + dt * 16 + quad * 4] = o4;
    }
}

// ---------------------------------------------------------------------------
// GEMM2: out(f32) = y[2048][1024](bf16) @ WpT^T (bf16 [1024][1024])
// R15/R18 form (measured best): 64x64 tile, BK=64, glds16, swizzled LDS.
// R24: batch from blockIdx.z.
// ---------------------------------------------------------------------------
__global__ __launch_bounds__(256, 2) void gemm2_proj_k(const ushort* __restrict__ Y,
                                                       const ushort* __restrict__ Bt,
                                                       float* __restrict__ out) {
    __shared__ __align__(16) ushort As[64 * 64];   // 8 KB, linear+swizzled
    __shared__ __align__(16) ushort Bs[64 * 64];   // 8 KB
    const size_t boff = (size_t)blockIdx.z * (2048u * 1024u);
    Y += boff; out += boff;
    const int tid = threadIdx.x;
    const int m0 = blockIdx.y * 64, n0 = blockIdx.x * 64;
    const int w = tid >> 6, lane = tid & 63, quad = lane >> 4, l16 = lane & 15;
    const int wr = w >> 1, wc = w & 1;
    const int K = 1024;
    const int srow = lane >> 3, sslot = lane & 7;

    floatx4 acc[2][2];
#pragma unroll
    for (int mt = 0; mt < 2; mt++)
#pragma unroll
        for (int nt = 0; nt < 2; nt++) acc[mt][nt] = (floatx4){0.f, 0.f, 0.f, 0.f};

    for (int k0 = 0; k0 < K; k0 += 64) {
        __syncthreads();
#pragma unroll
        for (int jj = 0; jj < 2; jj++) {
            const int reg = jj * 4 + w;
            const int row = reg * 8 + srow;
            const int cs = sslot ^ (row & 7);
            glds16(&Y[(size_t)(m0 + row) * K + k0 + cs * 8], &As[reg * 512]);
            glds16(&Bt[(size_t)(n0 + row) * K + k0 + cs * 8], &Bs[reg * 512]);
        }
        __syncthreads();

#pragma unroll
        for (int kk = 0; kk < 2; kk++) {
            short8 af[2], bfr[2];
#pragma unroll
            for (int mt = 0; mt < 2; mt++) {
                const int row = wr * 32 + mt * 16 + l16;
                const int slot = ((kk << 2) | quad) ^ (row & 7);
                af[mt] = *(short8*)&As[row * 64 + slot * 8];
            }
#pragma unroll
            for (int nt = 0; nt < 2; nt++) {
                const int row = wc * 32 + nt * 16 + l16;
                const int slot = ((kk << 2) | quad) ^ (row & 7);
                bfr[nt] = *(short8*)&Bs[row * 64 + slot * 8];
            }
#pragma unroll
            for (int mt = 0; mt < 2; mt++)
#pragma unroll
                for (int nt = 0; nt < 2; nt++) acc[mt][nt] = MFMA16(af[mt], bfr[nt], acc[mt][nt]);
        }
    }

#pragma unroll
    for (int mt = 0; mt < 2; mt++)
#pragma unroll
        for (int nt = 0; nt < 2; nt++) {
            const int n = n0 + wc * 32 + nt * 16 + l16;
#pragma unroll
            for (int r = 0; r < 4; r++) {
                const int m = m0 + wr * 32 + mt * 16 + quad * 4 + r;
                out[(size_t)m * 1024 + n] = acc[mt][nt][r];
            }
        }
}

// ---------------------------------------------------------------------------
extern "C" void kernel_launch(void* const* d_in, const int* in_sizes, int n_in,
                              void* d_out, int out_size, void* d_ws, size_t ws_size,
                              hipStream_t stream) {
    const float* x  = (const float*)d_in[0];   // [2,2048,1024] f32
    const float* Wa = (const float*)d_in[1];   // [1024,3072]  f32
    const float* Wp = (const float*)d_in[2];   // [1024,1024]  f32
    float* out = (float*)d_out;                // [2,2048,1024] f32

    const size_t PB = (size_t)2048 * 1024;     // per-batch elements
    ushort* wtA = (ushort*)(out + PB);         // 6 MB W_attn^T bf16 (d_out b1
                                               //  half; dead after gemm1, and
                                               //  gemm2-b1 fully overwrites it)
    float2* tab = (float2*)(wtA + (size_t)3 * 1024 * 1024);
                                               // 512 KB trig table (d_out b1
                                               //  tail; dead after rope)

    if (ws_size >= (size_t)36 * 1024 * 1024) {
        // -------- merged-batch path: 8 launches ---------------------------
        ushort* qbA = (ushort*)d_ws;           // [2] x 4 MB  q  [b][H,T,HD]
        ushort* kbA = qbA + 2 * PB;            // [2] x 4 MB  k
        ushort* vtA = qbA + 4 * PB;            // [2] x 4 MB  v^T
        ushort* ybA = qbA + 6 * PB;            // [2] x 4 MB  x_bf16 / y
        ushort* wtP = qbA + 8 * PB;            // 2 MB  W_proj^T

        tp_k<<<dim3(96, 32), 256, 0, stream>>>(Wa, wtA, 1024, 3072);
        trig_k<<<dim3(256), 256, 0, stream>>>(tab);
        tp_k<<<dim3(32, 32), 256, 0, stream>>>(Wp, wtP, 1024, 1024);

        cvt_k<<<dim3(4096), 256, 0, stream>>>(x, ybA);
        gemm1_qkv_k<<<dim3(24, 16, 2), 256, 0, stream>>>(ybA, wtA, qbA, kbA, vtA);
        rope_k<<<dim3(16384), 256, 0, stream>>>(qbA, kbA, tab);
        attn_k<<<dim3(1024), 256, 0, stream>>>(qbA, kbA, vtA, ybA);
        gemm2_proj_k<<<dim3(16, 32, 2), 256, 0, stream>>>(ybA, wtP, out);
        return;
    }

    // -------- fallback: per-batch loop (same kernels, z=1 grids) ----------
    ushort* qb  = (ushort*)d_ws;               // 4 MB bf16 q
    ushort* kb  = qb + PB;                     // 4 MB bf16 k
    ushort* vtb = kb + PB;                     // 4 MB bf16 v^T
    ushort* yb  = vtb + PB;                    // 4 MB bf16 y / x_bf16
    const bool hoistWp = ws_size >= (size_t)18 * 1024 * 1024;
    ushort* wtP_stable = yb + PB;              // d_ws + 16MB (only if hoistWp)

    tp_k<<<dim3(96, 32), 256, 0, stream>>>(Wa, wtA, 1024, 3072);
    trig_k<<<dim3(256), 256, 0, stream>>>(tab);
    if (hoistWp)
        tp_k<<<dim3(32, 32), 256, 0, stream>>>(Wp, wtP_stable, 1024, 1024);

    for (int b = 0; b < 2; b++) {
        cvt_k<<<dim3(2048), 256, 0, stream>>>(x + b * PB, yb);        // xb in yb slot
        gemm1_qkv_k<<<dim3(24, 16, 1), 256, 0, stream>>>(yb, wtA, qb, kb, vtb);
        rope_k<<<dim3(8192), 256, 0, stream>>>(qb, kb, tab);
        attn_k<<<dim3(512), 256, 0, stream>>>(qb, kb, vtb, yb);       // y over xb
        if (hoistWp) {
            gemm2_proj_k<<<dim3(16, 32, 1), 256, 0, stream>>>(yb, wtP_stable, out + b * PB);
        } else {
            tp_k<<<dim3(32, 32), 256, 0, stream>>>(Wp, qb, 1024, 1024);  // over dead q
            gemm2_proj_k<<<dim3(16, 32, 1), 256, 0, stream>>>(yb, qb, out + b * PB);
        }
    }
}

// Round 18
// 199.559 us; speedup vs baseline: 1.0776x; 1.0226x over previous
//
#include <hip/hip_runtime.h>

// ---------------------------------------------------------------------------
// qkv = x@W_attn; RoPE(q,k); flash-attn; y@W_proj
// B=2, T=2048, C=1024, H=16, HD=64.  I/O fp32; internal tensors bf16.
//
// R29 (R27 measured 204.07us; attn back on top at 48.6us, VALUBusy 36%,
// Occ 21% -> latency-bound chain with issue headroom; occupancy path is
// closed (R25 null)):
//  * attn processes TWO q-tiles per block: qtA=31-g (heavy) + qtB=g (light),
//    same head -> shared K/V staging (halves attn's K/V FETCH) and two
//    INDEPENDENT softmax chains give in-wave ILP to fill stall slots.
//    Per-block work = nktA+nktB = 17 chain-units for every g (self-balanced).
//    B active while kt2 < nktB (wave-uniform; nktB <= nktA).  Ps reused
//    A-then-B (same-wave DS ops are in-order).  Peak ~130-150 VGPR < 256 cap.
//    Grid: 512 merged (b = bid>>8) / 256 fallback.
//  * everything else byte-identical to measured R27 (gemm1 128x128, gemm2
//    R18-form, rope table, merged launches, attn R26 softmax).
// ---------------------------------------------------------------------------

typedef __attribute__((ext_vector_type(8))) short short8;   // 8 bf16 = 4 VGPRs
typedef __attribute__((ext_vector_type(4))) float floatx4;  // MFMA C/D frag

__device__ __forceinline__ ushort f2bf(float f) {
    unsigned x = __float_as_uint(f);
    x += 0x7fffu + ((x >> 16) & 1u);   // round-to-nearest-even
    return (ushort)(x >> 16);
}
__device__ __forceinline__ float bf2f(ushort u) {
    return __uint_as_float(((unsigned)u) << 16);
}
__device__ __forceinline__ float exp2fast(float x) {   // 2^x, raw v_exp_f32
    float r;
    asm("v_exp_f32 %0, %1" : "=v"(r) : "v"(x));
    return r;
}
__device__ __forceinline__ unsigned cvtpk_bf16(float lo, float hi) {
    unsigned r;                                        // [bf16(hi)|bf16(lo)]
    asm("v_cvt_pk_bf16_f32 %0, %1, %2" : "=v"(r) : "v"(lo), "v"(hi));
    return r;
}

#define MFMA16(a, b, c) __builtin_amdgcn_mfma_f32_16x16x32_bf16((a), (b), (c), 0, 0, 0)

// async global->LDS, 16 bytes per lane.  LDS dest must be wave-uniform base;
// HW writes base + lane*16.  Global src is per-lane.
__device__ __forceinline__ void glds16(const ushort* g, ushort* l) {
    __builtin_amdgcn_global_load_lds(
        (const __attribute__((address_space(1))) unsigned int*)g,
        (__attribute__((address_space(3))) unsigned int*)l, 16, 0, 0);
}

// ---------------------------------------------------------------------------
// Transpose + cvt: src f32 [R][C] -> dst bf16 [C][R].  32x32 tiles via LDS.
// ---------------------------------------------------------------------------
__global__ __launch_bounds__(256) void tp_k(const float* __restrict__ src,
                                            ushort* __restrict__ dst,
                                            int R, int C) {
    __shared__ ushort t[32][34];
    const int c0 = blockIdx.x * 32, r0 = blockIdx.y * 32;
    const int tr = threadIdx.x >> 5, tc = threadIdx.x & 31;
#pragma unroll
    for (int j = 0; j < 4; j++)
        t[tr + j * 8][tc] = f2bf(src[(size_t)(r0 + tr + j * 8) * C + c0 + tc]);
    __syncthreads();
#pragma unroll
    for (int j = 0; j < 4; j++)
        dst[(size_t)(c0 + tr + j * 8) * R + r0 + tc] = t[tc][tr + j * 8];
}

// ---------------------------------------------------------------------------
// cvt: f32 -> bf16, 4 elems/thread.
// ---------------------------------------------------------------------------
__global__ __launch_bounds__(256) void cvt_k(const float* __restrict__ src,
                                             ushort* __restrict__ dst) {
    const size_t i = ((size_t)blockIdx.x * 256 + threadIdx.x) * 4;
    float4 t4 = *(const float4*)&src[i];
    *(ushort4*)&dst[i] = make_ushort4(f2bf(t4.x), f2bf(t4.y), f2bf(t4.z), f2bf(t4.w));
}

// ---------------------------------------------------------------------------
// trig table: tab[t][j] = (cos(t * 10000^(-j/32)), sin(...)), f64 math
// identical to the original in-rope computation (bit-identical results).
// ---------------------------------------------------------------------------
__global__ __launch_bounds__(256) void trig_k(float2* __restrict__ tab) {
    const int idx = blockIdx.x * 256 + threadIdx.x;   // [0, 65536)
    const int t = idx >> 5, j = idx & 31;
    const double inv = pow(10000.0, -(double)j / 32.0);
    const double ang = (double)t * inv;
    tab[idx] = make_float2((float)cos(ang), (float)sin(ang));
}

// ---------------------------------------------------------------------------
// GEMM1: qkv = xb[2048][1024](bf16) @ WaT^T (Bt bf16 [3072][1024])
//   -> q: [H,T,HD]  k: [H,T,HD]  v^T: [H,HD,T]  (bf16)
// R27: 128x128 tile (grid 24x16xZ), BK=64, glds16, swizzled LDS.
// ---------------------------------------------------------------------------
__global__ __launch_bounds__(256, 3) void gemm1_qkv_k(const ushort* __restrict__ Ab,
                                                      const ushort* __restrict__ Bt,
                                                      ushort* __restrict__ qb,
                                                      ushort* __restrict__ kb,
                                                      ushort* __restrict__ vtb) {
    __shared__ __align__(16) ushort As[128 * 64];  // 16 KB, linear+swizzled
    __shared__ __align__(16) ushort Bs[128 * 64];  // 16 KB
    const size_t boff = (size_t)blockIdx.z * (2048u * 1024u);
    Ab += boff; qb += boff; kb += boff; vtb += boff;
    const int tid = threadIdx.x;
    const int m0 = blockIdx.y * 128, n0 = blockIdx.x * 128;
    const int w = tid >> 6, lane = tid & 63, quad = lane >> 4, l16 = lane & 15;
    const int wr = w >> 1, wc = w & 1;
    const int K = 1024;
    const int srow = lane >> 3, sslot = lane & 7;  // staging sub-row / slot

    floatx4 acc[4][4];
#pragma unroll
    for (int mt = 0; mt < 4; mt++)
#pragma unroll
        for (int nt = 0; nt < 4; nt++) acc[mt][nt] = (floatx4){0.f, 0.f, 0.f, 0.f};

    for (int k0 = 0; k0 < K; k0 += 64) {
        __syncthreads();   // all waves done reading prev tile
#pragma unroll
        for (int jj = 0; jj < 4; jj++) {
            const int reg = jj * 4 + w;
            const int row = reg * 8 + srow;
            const int cs = sslot ^ (row & 7);
            glds16(&Ab[(size_t)(m0 + row) * K + k0 + cs * 8], &As[reg * 512]);
        }
#pragma unroll
        for (int jj = 0; jj < 4; jj++) {
            const int reg = jj * 4 + w;
            const int row = reg * 8 + srow;
            const int cs = sslot ^ (row & 7);
            glds16(&Bt[(size_t)(n0 + row) * K + k0 + cs * 8], &Bs[reg * 512]);
        }
        __syncthreads();   // compiler drains vmcnt(0) before barrier

#pragma unroll
        for (int kk = 0; kk < 2; kk++) {
            short8 af[4], bfr[4];
#pragma unroll
            for (int mt = 0; mt < 4; mt++) {
                const int row = wr * 64 + mt * 16 + l16;
                const int slot = ((kk << 2) | quad) ^ (row & 7);
                af[mt] = *(short8*)&As[row * 64 + slot * 8];
            }
#pragma unroll
            for (int nt = 0; nt < 4; nt++) {
                const int row = wc * 64 + nt * 16 + l16;
                const int slot = ((kk << 2) | quad) ^ (row & 7);
                bfr[nt] = *(short8*)&Bs[row * 64 + slot * 8];
            }
#pragma unroll
            for (int mt = 0; mt < 4; mt++)
#pragma unroll
                for (int nt = 0; nt < 4; nt++) acc[mt][nt] = MFMA16(af[mt], bfr[nt], acc[mt][nt]);
        }
    }

    // Epilogue [R5-R14 verified 128x128 formulas]
#pragma unroll
    for (int nt = 0; nt < 4; nt++) {
        const int n = n0 + wc * 64 + nt * 16 + l16;
        const int seg = n >> 10;          // 0=q 1=k 2=v
        const int cn = n & 1023;
        const int h = cn >> 6, d = cn & 63;
#pragma unroll
        for (int mt = 0; mt < 4; mt++) {
#pragma unroll
            for (int r = 0; r < 4; r++) {
                const int t = m0 + wr * 64 + mt * 16 + quad * 4 + r;
                const ushort v = f2bf(acc[mt][nt][r]);
                if (seg == 0)      qb[((size_t)h * 2048 + t) * 64 + d] = v;
                else if (seg == 1) kb[((size_t)h * 2048 + t) * 64 + d] = v;
                else               vtb[((size_t)h * 64 + d) * 2048 + t] = v;
            }
        }
    }
}

// ---------------------------------------------------------------------------
// RoPE (roll variant), table-based trig.  Math identical to verified R5-R11.
// ---------------------------------------------------------------------------
__global__ __launch_bounds__(256) void rope_k(ushort* __restrict__ q,
                                              ushort* __restrict__ k,
                                              const float2* __restrict__ tab) {
    const int wid = blockIdx.x * 4 + (threadIdx.x >> 6);  // row
    const int lane = threadIdx.x & 63;
    const int t = wid & 2047;
    const float2 cs = tab[t * 32 + (lane & 31)];
    const float c = cs.x;
    const float s = cs.y;
    const size_t base = (size_t)wid * 64;

    float qv = bf2f(q[base + lane]);
    float qp = __shfl(qv, (lane + 63) & 63, 64);
    q[base + lane] = f2bf(qv * c + qp * s);

    float kv = bf2f(k[base + lane]);
    float kp = __shfl(kv, (lane + 63) & 63, 64);
    k[base + lane] = f2bf(kv * c + kp * s);
}

// ---------------------------------------------------------------------------
// Flash attention (causal), transposed form.
// R13: no Ps barrier.  R21: KVBLK=128 + glds16 staging + exact-skip + setprio.
// R26: mask-skip, exp2-domain softmax, cvt_pk P->bf16.
// R29: TWO q-tiles per block (qtA=31-g heavy, qtB=g light, same head):
//      shared K/V staging, independent chains (in-wave ILP), Ps reused
//      A-then-B (same-wave DS in-order).  Per-block work = 17 chain-units
//      for all g.  Grid 512 merged (b=bid>>8) / 256 fallback.
// ---------------------------------------------------------------------------
__global__ __launch_bounds__(256, 2) void attn_k(const ushort* __restrict__ q,
                                                 const ushort* __restrict__ k,
                                                 const ushort* __restrict__ vt,
                                                 ushort* __restrict__ y) {
    __shared__ __align__(16) ushort Ks[128 * 64];   // [key][d]  16 KB swz
    __shared__ __align__(16) ushort Vs[64 * 128];   // [d][key]  16 KB swz
    __shared__ __align__(16) ushort Ps[4][16][136]; // per-wave P^T [qrow][key]

    const int bid = blockIdx.x;
    const int b = bid >> 8;            // batch (0 under fallback grid 256)
    const int r8 = bid & 255;
    const int g = r8 >> 4;             // pair index 0..15
    const int h = r8 & 15;
    const int qtA = 31 - g, qtB = g;
    const size_t boff = (size_t)b * (2048u * 1024u);
    q += boff; k += boff; vt += boff; y += boff;
    const int tid = threadIdx.x, w = tid >> 6, lane = tid & 63;
    const int quad = lane >> 4, l16 = lane & 15;
    const int srow8 = lane >> 3, sslot8 = lane & 7;   // K staging (8 rows/KB)
    const int srow4 = lane >> 4, sslot16 = lane & 15; // V staging (4 rows/KB)

    const int qrowA = qtA * 64 + w * 16 + l16;
    const int qrowB = qtB * 64 + w * 16 + l16;
    const int wrow0A = qtA * 64 + w * 16;
    const int wrow0B = qtB * 64 + w * 16;
    const int nktA = (qtA >> 1) + 1;   // 128-key tiles (B: nktB <= nktA)
    const int nktB = (qtB >> 1) + 1;
    const float SC = 0.125f * 1.44269504f;  // score scale folded with log2(e)

    short8 qaA0, qaA1, qaB0, qaB1;
    {
        const ushort* qp = q + ((size_t)h * 2048 + qrowA) * 64 + quad * 8;
        qaA0 = *(const short8*)(qp);
        qaA1 = *(const short8*)(qp + 32);
        const ushort* qp2 = q + ((size_t)h * 2048 + qrowB) * 64 + quad * 8;
        qaB0 = *(const short8*)(qp2);
        qaB1 = *(const short8*)(qp2 + 32);
    }

    floatx4 OA[4], OB[4];
#pragma unroll
    for (int dt = 0; dt < 4; dt++) {
        OA[dt] = (floatx4){0.f, 0.f, 0.f, 0.f};
        OB[dt] = (floatx4){0.f, 0.f, 0.f, 0.f};
    }
    float MA = -30000.f, LA = 0.f, MB = -30000.f, LB = 0.f;

    for (int kt2 = 0; kt2 < nktA; kt2++) {
        const int kbase = kt2 * 128;
        __syncthreads();   // all waves done reading prev tile's LDS
        // K: 128 rows x 64 (128B rows, 8 chunks), 16 regions of 8 rows.
#pragma unroll
        for (int jj = 0; jj < 4; jj++) {
            const int reg = jj * 4 + w;
            const int row = reg * 8 + srow8;
            const int cs = sslot8 ^ (row & 7);
            glds16(&k[((size_t)h * 2048 + kbase + row) * 64 + cs * 8], &Ks[reg * 512]);
        }
        // V^T: 64 rows x 128 (256B rows, 16 chunks), 16 regions of 4 rows.
#pragma unroll
        for (int jj = 0; jj < 4; jj++) {
            const int reg = jj * 4 + w;
            const int row = reg * 4 + srow4;
            const int cs = sslot16 ^ (row & 15);
            glds16(&vt[((size_t)h * 64 + row) * 2048 + kbase + cs * 8], &Vs[reg * 512]);
        }
        __syncthreads();   // staging complete (vmcnt(0) drained at barrier)

        // ================= tile A (always active) =================
        {
            floatx4 s[8];
            __builtin_amdgcn_s_setprio(1);
#pragma unroll
            for (int nt = 0; nt < 8; nt++) {
                const int row = nt * 16 + l16;
                short8 ka0 = *(short8*)&Ks[row * 64 + ((quad ^ (row & 7)) * 8)];
                short8 ka1 = *(short8*)&Ks[row * 64 + (((4 | quad) ^ (row & 7)) * 8)];
                floatx4 z = (floatx4){0.f, 0.f, 0.f, 0.f};
                z = MFMA16(ka0, qaA0, z);
                z = MFMA16(ka1, qaA1, z);
                s[nt] = z;
            }
            __builtin_amdgcn_s_setprio(0);

            if (kbase + 127 <= wrow0A) {
#pragma unroll
                for (int nt = 0; nt < 8; nt++)
#pragma unroll
                    for (int r = 0; r < 4; r++) s[nt][r] *= SC;
            } else {
#pragma unroll
                for (int nt = 0; nt < 8; nt++)
#pragma unroll
                    for (int r = 0; r < 4; r++) {
                        const int kidx = kbase + nt * 16 + quad * 4 + r;
                        const float vv = s[nt][r] * SC;
                        s[nt][r] = (kidx > qrowA) ? -30000.f : vv;
                    }
            }

            float mr[8];
#pragma unroll
            for (int nt = 0; nt < 8; nt++)
                mr[nt] = fmaxf(fmaxf(s[nt][0], s[nt][1]), fmaxf(s[nt][2], s[nt][3]));
            float mx = fmaxf(fmaxf(fmaxf(mr[0], mr[1]), fmaxf(mr[2], mr[3])),
                             fmaxf(fmaxf(mr[4], mr[5]), fmaxf(mr[6], mr[7])));
            mx = fmaxf(mx, __shfl_xor(mx, 16, 64));
            mx = fmaxf(mx, __shfl_xor(mx, 32, 64));

            if (!__all(mx <= MA)) {
                const float Mn = fmaxf(MA, mx);
                const float alpha = exp2fast(MA - Mn);
                LA *= alpha;
#pragma unroll
                for (int dt = 0; dt < 4; dt++) OA[dt] *= alpha;
                MA = Mn;
            }

            float sum = 0.f;
#pragma unroll
            for (int nt = 0; nt < 8; nt++)
#pragma unroll
                for (int r = 0; r < 4; r++) {
                    const float pv = exp2fast(s[nt][r] - MA);
                    s[nt][r] = pv;
                    sum += pv;
                }
            sum += __shfl_xor(sum, 16, 64);
            sum += __shfl_xor(sum, 32, 64);
            LA += sum;

#pragma unroll
            for (int nt = 0; nt < 8; nt++) {
                uint2 pk2;
                pk2.x = cvtpk_bf16(s[nt][0], s[nt][1]);
                pk2.y = cvtpk_bf16(s[nt][2], s[nt][3]);
                *(uint2*)&Ps[w][l16][nt * 16 + quad * 4] = pk2;
            }
            short8 pb[4];
#pragma unroll
            for (int ks = 0; ks < 4; ks++)
                pb[ks] = *(short8*)&Ps[w][l16][ks * 32 + quad * 8];
            __builtin_amdgcn_s_setprio(1);
#pragma unroll
            for (int dt = 0; dt < 4; dt++) {
                const int row = dt * 16 + l16;
#pragma unroll
                for (int ks = 0; ks < 4; ks++) {
                    const int cc = (ks * 4 + quad) ^ (row & 15);
                    short8 va = *(short8*)&Vs[row * 128 + cc * 8];
                    OA[dt] = MFMA16(va, pb[ks], OA[dt]);
                }
            }
            __builtin_amdgcn_s_setprio(0);
        }

        // ================= tile B (active while kt2 < nktB) =================
        if (kt2 < nktB) {
            floatx4 s[8];
            __builtin_amdgcn_s_setprio(1);
#pragma unroll
            for (int nt = 0; nt < 8; nt++) {
                const int row = nt * 16 + l16;
                short8 ka0 = *(short8*)&Ks[row * 64 + ((quad ^ (row & 7)) * 8)];
                short8 ka1 = *(short8*)&Ks[row * 64 + (((4 | quad) ^ (row & 7)) * 8)];
                floatx4 z = (floatx4){0.f, 0.f, 0.f, 0.f};
                z = MFMA16(ka0, qaB0, z);
                z = MFMA16(ka1, qaB1, z);
                s[nt] = z;
            }
            __builtin_amdgcn_s_setprio(0);

            if (kbase + 127 <= wrow0B) {
#pragma unroll
                for (int nt = 0; nt < 8; nt++)
#pragma unroll
                    for (int r = 0; r < 4; r++) s[nt][r] *= SC;
            } else {
#pragma unroll
                for (int nt = 0; nt < 8; nt++)
#pragma unroll
                    for (int r = 0; r < 4; r++) {
                        const int kidx = kbase + nt * 16 + quad * 4 + r;
                        const float vv = s[nt][r] * SC;
                        s[nt][r] = (kidx > qrowB) ? -30000.f : vv;
                    }
            }

            float mr[8];
#pragma unroll
            for (int nt = 0; nt < 8; nt++)
                mr[nt] = fmaxf(fmaxf(s[nt][0], s[nt][1]), fmaxf(s[nt][2], s[nt][3]));
            float mx = fmaxf(fmaxf(fmaxf(mr[0], mr[1]), fmaxf(mr[2], mr[3])),
                             fmaxf(fmaxf(mr[4], mr[5]), fmaxf(mr[6], mr[7])));
            mx = fmaxf(mx, __shfl_xor(mx, 16, 64));
            mx = fmaxf(mx, __shfl_xor(mx, 32, 64));

            if (!__all(mx <= MB)) {
                const float Mn = fmaxf(MB, mx);
                const float alpha = exp2fast(MB - Mn);
                LB *= alpha;
#pragma unroll
                for (int dt = 0; dt < 4; dt++) OB[dt] *= alpha;
                MB = Mn;
            }

            float sum = 0.f;
#pragma unroll
            for (int nt = 0; nt < 8; nt++)
#pragma unroll
                for (int r = 0; r < 4; r++) {
                    const float pv = exp2fast(s[nt][r] - MB);
                    s[nt][r] = pv;
                    sum += pv;
                }
            sum += __shfl_xor(sum, 16, 64);
            sum += __shfl_xor(sum, 32, 64);
            LB += sum;

#pragma unroll
            for (int nt = 0; nt < 8; nt++) {
                uint2 pk2;
                pk2.x = cvtpk_bf16(s[nt][0], s[nt][1]);
                pk2.y = cvtpk_bf16(s[nt][2], s[nt][3]);
                *(uint2*)&Ps[w][l16][nt * 16 + quad * 4] = pk2;
            }
            short8 pb[4];
#pragma unroll
            for (int ks = 0; ks < 4; ks++)
                pb[ks] = *(short8*)&Ps[w][l16][ks * 32 + quad * 8];
            __builtin_amdgcn_s_setprio(1);
#pragma unroll
            for (int dt = 0; dt < 4; dt++) {
                const int row = dt * 16 + l16;
#pragma unroll
                for (int ks = 0; ks < 4; ks++) {
                    const int cc = (ks * 4 + quad) ^ (row & 15);
                    short8 va = *(short8*)&Vs[row * 128 + cc * 8];
                    OB[dt] = MFMA16(va, pb[ks], OB[dt]);
                }
            }
            __builtin_amdgcn_s_setprio(0);
        }
    }

    {
        const float rl = 1.0f / LA;
#pragma unroll
        for (int dt = 0; dt < 4; dt++) {
            ushort4 o4 = make_ushort4(f2bf(OA[dt][0] * rl), f2bf(OA[dt][1] * rl),
                                      f2bf(OA[dt][2] * rl), f2bf(OA[dt][3] * rl));
            *(ushort4*)&y[(size_t)qrowA * 1024 + h * 64 + dt * 16 + quad * 4] = o4;
        }
    }
    {
        const float rl = 1.0f / LB;
#pragma unroll
        for (int dt = 0; dt < 4; dt++) {
            ushort4 o4 = make_ushort4(f2bf(OB[dt][0] * rl), f2bf(OB[dt][1] * rl),
                                      f2bf(OB[dt][2] * rl), f2bf(OB[dt][3] * rl));
            *(ushort4*)&y[(size_t)qrowB * 1024 + h * 64 + dt * 16 + quad * 4] = o4;
        }
    }
}

// ---------------------------------------------------------------------------
// GEMM2: out(f32) = y[2048][1024](bf16) @ WpT^T (bf16 [1024][1024])
// R15/R18 form (measured best): 64x64 tile, BK=64, glds16, swizzled LDS.
// ---------------------------------------------------------------------------
__global__ __launch_bounds__(256, 2) void gemm2_proj_k(const ushort* __restrict__ Y,
                                                       const ushort* __restrict__ Bt,
                                                       float* __restrict__ out) {
    __shared__ __align__(16) ushort As[64 * 64];   // 8 KB, linear+swizzled
    __shared__ __align__(16) ushort Bs[64 * 64];   // 8 KB
    const size_t boff = (size_t)blockIdx.z * (2048u * 1024u);
    Y += boff; out += boff;
    const int tid = threadIdx.x;
    const int m0 = blockIdx.y * 64, n0 = blockIdx.x * 64;
    const int w = tid >> 6, lane = tid & 63, quad = lane >> 4, l16 = lane & 15;
    const int wr = w >> 1, wc = w & 1;
    const int K = 1024;
    const int srow = lane >> 3, sslot = lane & 7;

    floatx4 acc[2][2];
#pragma unroll
    for (int mt = 0; mt < 2; mt++)
#pragma unroll
        for (int nt = 0; nt < 2; nt++) acc[mt][nt] = (floatx4){0.f, 0.f, 0.f, 0.f};

    for (int k0 = 0; k0 < K; k0 += 64) {
        __syncthreads();
#pragma unroll
        for (int jj = 0; jj < 2; jj++) {
            const int reg = jj * 4 + w;
            const int row = reg * 8 + srow;
            const int cs = sslot ^ (row & 7);
            glds16(&Y[(size_t)(m0 + row) * K + k0 + cs * 8], &As[reg * 512]);
            glds16(&Bt[(size_t)(n0 + row) * K + k0 + cs * 8], &Bs[reg * 512]);
        }
        __syncthreads();

#pragma unroll
        for (int kk = 0; kk < 2; kk++) {
            short8 af[2], bfr[2];
#pragma unroll
            for (int mt = 0; mt < 2; mt++) {
                const int row = wr * 32 + mt * 16 + l16;
                const int slot = ((kk << 2) | quad) ^ (row & 7);
                af[mt] = *(short8*)&As[row * 64 + slot * 8];
            }
#pragma unroll
            for (int nt = 0; nt < 2; nt++) {
                const int row = wc * 32 + nt * 16 + l16;
                const int slot = ((kk << 2) | quad) ^ (row & 7);
                bfr[nt] = *(short8*)&Bs[row * 64 + slot * 8];
            }
#pragma unroll
            for (int mt = 0; mt < 2; mt++)
#pragma unroll
                for (int nt = 0; nt < 2; nt++) acc[mt][nt] = MFMA16(af[mt], bfr[nt], acc[mt][nt]);
        }
    }

#pragma unroll
    for (int mt = 0; mt < 2; mt++)
#pragma unroll
        for (int nt = 0; nt < 2; nt++) {
            const int n = n0 + wc * 32 + nt * 16 + l16;
#pragma unroll
            for (int r = 0; r < 4; r++) {
                const int m = m0 + wr * 32 + mt * 16 + quad * 4 + r;
                out[(size_t)m * 1024 + n] = acc[mt][nt][r];
            }
        }
}

// ---------------------------------------------------------------------------
extern "C" void kernel_launch(void* const* d_in, const int* in_sizes, int n_in,
                              void* d_out, int out_size, void* d_ws, size_t ws_size,
                              hipStream_t stream) {
    const float* x  = (const float*)d_in[0];   // [2,2048,1024] f32
    const float* Wa = (const float*)d_in[1];   // [1024,3072]  f32
    const float* Wp = (const float*)d_in[2];   // [1024,1024]  f32
    float* out = (float*)d_out;                // [2,2048,1024] f32

    const size_t PB = (size_t)2048 * 1024;     // per-batch elements
    ushort* wtA = (ushort*)(out + PB);         // 6 MB W_attn^T bf16 (d_out b1
                                               //  half; dead after gemm1, and
                                               //  gemm2-b1 fully overwrites it)
    float2* tab = (float2*)(wtA + (size_t)3 * 1024 * 1024);
                                               // 512 KB trig table (d_out b1
                                               //  tail; dead after rope)

    if (ws_size >= (size_t)36 * 1024 * 1024) {
        // -------- merged-batch path: 8 launches ---------------------------
        ushort* qbA = (ushort*)d_ws;           // [2] x 4 MB  q  [b][H,T,HD]
        ushort* kbA = qbA + 2 * PB;            // [2] x 4 MB  k
        ushort* vtA = qbA + 4 * PB;            // [2] x 4 MB  v^T
        ushort* ybA = qbA + 6 * PB;            // [2] x 4 MB  x_bf16 / y
        ushort* wtP = qbA + 8 * PB;            // 2 MB  W_proj^T

        tp_k<<<dim3(96, 32), 256, 0, stream>>>(Wa, wtA, 1024, 3072);
        trig_k<<<dim3(256), 256, 0, stream>>>(tab);
        tp_k<<<dim3(32, 32), 256, 0, stream>>>(Wp, wtP, 1024, 1024);

        cvt_k<<<dim3(4096), 256, 0, stream>>>(x, ybA);
        gemm1_qkv_k<<<dim3(24, 16, 2), 256, 0, stream>>>(ybA, wtA, qbA, kbA, vtA);
        rope_k<<<dim3(16384), 256, 0, stream>>>(qbA, kbA, tab);
        attn_k<<<dim3(512), 256, 0, stream>>>(qbA, kbA, vtA, ybA);
        gemm2_proj_k<<<dim3(16, 32, 2), 256, 0, stream>>>(ybA, wtP, out);
        return;
    }

    // -------- fallback: per-batch loop (same kernels, z=1 grids) ----------
    ushort* qb  = (ushort*)d_ws;               // 4 MB bf16 q
    ushort* kb  = qb + PB;                     // 4 MB bf16 k
    ushort* vtb = kb + PB;                     // 4 MB bf16 v^T
    ushort* yb  = vtb + PB;                    // 4 MB bf16 y / x_bf16
    const bool hoistWp = ws_size >= (size_t)18 * 1024 * 1024;
    ushort* wtP_stable = yb + PB;              // d_ws + 16MB (only if hoistWp)

    tp_k<<<dim3(96, 32), 256, 0, stream>>>(Wa, wtA, 1024, 3072);
    trig_k<<<dim3(256), 256, 0, stream>>>(tab);
    if (hoistWp)
        tp_k<<<dim3(32, 32), 256, 0, stream>>>(Wp, wtP_stable, 1024, 1024);

    for (int b = 0; b < 2; b++) {
        cvt_k<<<dim3(2048), 256, 0, stream>>>(x + b * PB, yb);        // xb in yb slot
        gemm1_qkv_k<<<dim3(24, 16, 1), 256, 0, stream>>>(yb, wtA, qb, kb, vtb);
        rope_k<<<dim3(8192), 256, 0, stream>>>(qb, kb, tab);
        attn_k<<<dim3(256), 256, 0, stream>>>(qb, kb, vtb, yb);       // y over xb
        if (hoistWp) {
            gemm2_proj_k<<<dim3(16, 32, 1), 256, 0, stream>>>(yb, wtP_stable, out + b * PB);
        } else {
            tp_k<<<dim3(32, 32), 256, 0, stream>>>(Wp, qb, 1024, 1024);  // over dead q
            gemm2_proj_k<<<dim3(16, 32, 1), 256, 0, stream>>>(yb, qb, out + b * PB);
        }
    }
}